// Round 9
// baseline (1096.996 us; speedup 1.0000x reference)
//
#include <hip/hip_runtime.h>
#include <hip/hip_fp16.h>

#define BB 16
#define TT 4096
#define TSZ 64
#define DE 128
#define HH 256
#define LDIM 512
#define ODIM 10
#define NBLKS 6
#define EPSF 1e-5f
#define NC32 128          // 32-token chunks
#define NROWS (BB*TT)     // 65536

typedef _Float16 f16x8 __attribute__((ext_vector_type(8)));
typedef float f32x4 __attribute__((ext_vector_type(4)));
#define MFMA16(a,b,c) __builtin_amdgcn_mfma_f32_16x16x32_f16((a),(b),(c),0,0,0)

// ---- f16 weight region layout (offsets in halfs, base = ws + WOFF_W16) ----
enum : size_t {
  HOFF_BG = 0,                                  // [NBLK][512][128]  gamma*B rows (re|im)
  HOFF_WC = HOFF_BG + (size_t)NBLKS*512*128,    // [NBLK][128][512]  C-proj [d][hc]
  HOFF_W1 = HOFF_WC + (size_t)NBLKS*128*512,    // [NBLK][512][128]  W1^T [l][d]
  HOFF_W2 = HOFF_W1 + (size_t)NBLKS*512*128,    // [NBLK][128][256]  W2^T [d][g]
  HOFF_WE = HOFF_W2 + (size_t)NBLKS*128*256,    // [128][64]         Wenc^T
  HTOT_HALFS = HOFF_WE + 128*64
};

// ---- workspace layout (float offsets) ----
enum : size_t {
  WOFF_Y     = 0,                                    // __half [NROWS*DE]
  WOFF_H     = WOFF_Y + (size_t)NROWS*DE/2,          // __half [NROWS*DE]
  WOFF_W16   = WOFF_H + (size_t)NROWS*DE/2,          // f16 weights
  WOFF_LAM   = WOFF_W16 + (HTOT_HALFS+1)/2,          // [NBLK][256][2]
  WOFF_LAML  = WOFF_LAM + (size_t)NBLKS*HH*2,        // [NBLK][256][2] lam^32
  WOFF_SL    = WOFF_LAML + (size_t)NBLKS*HH*2,       // [B][128][256][2]
  WOFF_CARRY = WOFF_SL + (size_t)BB*NC32*HH*2,       // [B][128][256][2]
  WOFF_STATS = WOFF_CARRY + (size_t)BB*NC32*HH*2,    // [NBLK+1][2][128]
  WOFF_POOL  = WOFF_STATS + (size_t)(NBLKS+1)*2*DE,  // [B][128]
  WS_FLOATS  = WOFF_POOL + (size_t)BB*DE
};

// ============================ prep ============================
__global__ __launch_bounds__(256) void k_prep(
    const float* __restrict__ nu_log, const float* __restrict__ theta_log,
    const float* __restrict__ B_re, const float* __restrict__ B_im,
    const float* __restrict__ C_re, const float* __restrict__ C_im,
    const float* __restrict__ W1g, const float* __restrict__ W2g,
    const float* __restrict__ Wenc, float* __restrict__ ws)
{
  const int i = blockIdx.x, h = threadIdx.x;
  __half* w16 = (__half*)(ws + WOFF_W16);
  const float nu  = expf(nu_log[i*HH+h]);
  const float th  = expf(theta_log[i*HH+h]);
  const float mod = expf(-nu);
  const float lr = mod*cosf(th), li = mod*sinf(th);
  const float gamma = sqrtf(fmaxf(1.0f - mod*mod, 1e-8f));
  ws[WOFF_LAM + ((size_t)i*HH+h)*2+0] = lr;
  ws[WOFF_LAM + ((size_t)i*HH+h)*2+1] = li;
  {
    float ar = lr, ai = li;
    #pragma unroll
    for (int q = 0; q < 5; q++) { float nr=ar*ar-ai*ai, ni=2.0f*ar*ai; ar=nr; ai=ni; }
    ws[WOFF_LAML + ((size_t)i*HH+h)*2+0] = ar;   // lam^32
    ws[WOFF_LAML + ((size_t)i*HH+h)*2+1] = ai;
  }
  // BG [512][128]
  {
    __half* bg = w16 + HOFF_BG + (size_t)i*512*128;
    const float* bre = B_re + ((size_t)i*HH+h)*DE;
    const float* bim = B_im + ((size_t)i*HH+h)*DE;
    for (int d = 0; d < DE; d++) {
      bg[(size_t)h*128 + d]       = __float2half(bre[d]*gamma);
      bg[(size_t)(256+h)*128 + d] = __float2half(bim[d]*gamma);
    }
  }
  // WC [128][512]
  {
    __half* wc = w16 + HOFF_WC + (size_t)i*128*512;
    const float* cre = C_re + (size_t)i*DE*HH;
    const float* cim = C_im + (size_t)i*DE*HH;
    for (int d = 0; d < DE; d++) {
      wc[(size_t)d*512 + h]       = __float2half( cre[(size_t)d*HH + h]);
      wc[(size_t)d*512 + 256 + h] = __float2half(-cim[(size_t)d*HH + h]);
    }
  }
  // W1T [512][128]
  {
    __half* w1t = w16 + HOFF_W1 + (size_t)i*512*128;
    for (int d = 0; d < DE; d++) {
      w1t[(size_t)h*128 + d]       = __float2half(W1g[((size_t)i*DE + d)*LDIM + h]);
      w1t[(size_t)(256+h)*128 + d] = __float2half(W1g[((size_t)i*DE + d)*LDIM + 256 + h]);
    }
  }
  // W2T [128][256]
  if (h < 128) {
    __half* w2t = w16 + HOFF_W2 + (size_t)i*128*256;
    for (int g = 0; g < 256; g++)
      w2t[(size_t)h*256 + g] = __float2half(W2g[((size_t)i*256 + g)*DE + h]);
  }
  // WencT [128][64]
  if (i == 0 && h < 128) {
    __half* wet = w16 + HOFF_WE;
    for (int k = 0; k < TSZ; k++)
      wet[(size_t)h*TSZ + k] = __float2half(Wenc[(size_t)k*DE + h]);
  }
}

// ============================ encoder ============================
__global__ __launch_bounds__(512) void k_enc(
    const float* __restrict__ x, const float* __restrict__ benc, float* __restrict__ ws)
{
  __shared__ __half XT[64*72];
  const int tid = threadIdx.x, w = tid >> 6, l = tid & 63;
  const size_t row0 = (size_t)blockIdx.x * 64;
  {
    const float4* xg = (const float4*)(x + row0*TSZ);
    for (int idx = tid; idx < 1024; idx += 512) {
      float4 v = xg[idx];
      const int r = idx >> 4, c4 = (idx & 15)*4;
      *(__half2*)&XT[r*72 + c4]     = __half2{__float2half(v.x), __float2half(v.y)};
      *(__half2*)&XT[r*72 + c4 + 2] = __half2{__float2half(v.z), __float2half(v.w)};
    }
  }
  __syncthreads();
  const __half* wet = (const __half*)(ws + WOFF_W16) + HOFF_WE;
  const int n0 = w*16;
  f32x4 acc[4];
  #pragma unroll
  for (int mt = 0; mt < 4; mt++) acc[mt] = (f32x4)(0.0f);
  #pragma unroll
  for (int k0 = 0; k0 < 64; k0 += 32) {
    f16x8 bf = *(const f16x8*)&wet[(size_t)(n0 + (l&15))*64 + k0 + (l>>4)*8];
    #pragma unroll
    for (int mt = 0; mt < 4; mt++) {
      f16x8 af = *(const f16x8*)&XT[(mt*16 + (l&15))*72 + k0 + (l>>4)*8];
      acc[mt] = MFMA16(af, bf, acc[mt]);
    }
  }
  const int d = n0 + (l&15);
  const float be = benc[d];
  float s = 0.0f, ss = 0.0f;
  __half* y = (__half*)(ws + WOFF_Y);
  #pragma unroll
  for (int mt = 0; mt < 4; mt++)
    #pragma unroll
    for (int j = 0; j < 4; j++) {
      const int t = mt*16 + (l>>4)*4 + j;
      const float v = acc[mt][j] + be;
      y[(row0 + t)*DE + d] = __float2half(v);
      s += v; ss += v*v;
    }
  s  += __shfl_xor(s, 16);  s  += __shfl_xor(s, 32);
  ss += __shfl_xor(ss, 16); ss += __shfl_xor(ss, 32);
  if (l < 16) {
    atomicAdd(ws + WOFF_STATS + d, s);
    atomicAdd(ws + WOFF_STATS + DE + d, ss);
  }
}

// ============================ k_A: BN + B-proj + LDS scan -> SL only ============================
__global__ __launch_bounds__(512, 4) void k_A(
    const __half* __restrict__ hin, float* __restrict__ ws,
    const float* __restrict__ bnsg, const float* __restrict__ bnbg, int iblk)
{
  __shared__ __half U[32*136];     // 8.5 KB
  __shared__ __half BU[32*520];    // 32.5 KB
  __shared__ float AC[256];
  const int tid = threadIdx.x, w = tid >> 6, l = tid & 63, q = l >> 4, r = l & 15;
  const int b = blockIdx.y, cbg = blockIdx.x;   // 32 groups × 4 chunks
  const int h = tid & 255;
  if (tid < 128) {
    const float inv = 1.0f / (float)NROWS;
    const float s  = ws[WOFF_STATS + ((size_t)iblk*2+0)*DE + tid];
    const float sq = ws[WOFF_STATS + ((size_t)iblk*2+1)*DE + tid];
    const float mean = s*inv;
    const float var  = sq*inv - mean*mean;
    const float a = rsqrtf(var + EPSF) * bnsg[iblk*DE + tid];
    AC[tid]       = a;
    AC[128 + tid] = bnbg[iblk*DE + tid] - mean*a;
  }
  const __half* BG = (const __half*)(ws + WOFF_W16) + HOFF_BG + (size_t)iblk*512*128;
  const int n0 = w*64;
  const float lr = ws[WOFF_LAM + ((size_t)iblk*HH+h)*2+0];
  const float li = ws[WOFF_LAM + ((size_t)iblk*HH+h)*2+1];
  // weights (tile-invariant)
  f16x8 bg4[4][4];
  #pragma unroll
  for (int nt = 0; nt < 4; nt++)
    #pragma unroll
    for (int k = 0; k < 4; k++)
      bg4[nt][k] = *(const f16x8*)&BG[(size_t)(n0 + nt*16 + r)*128 + k*32 + q*8];
  __syncthreads();

  for (int it = 0; it < 4; it++) {
    const int cb = cbg*4 + it;
    const int row0 = b*TT + cb*32;
    // BN -> U
    {
      const int row = tid >> 4, d0 = (tid & 15)*8;
      f16x8 hv = *(const f16x8*)(hin + (size_t)(row0+row)*DE + d0);
      f16x8 uv;
      #pragma unroll
      for (int j = 0; j < 8; j++)
        uv[j] = (_Float16)((float)hv[j]*AC[d0+j] + AC[128+d0+j]);
      *(f16x8*)&U[row*136 + d0] = uv;
    }
    __syncthreads();
    // B-proj -> BU
    {
      f32x4 acc[2][4];
      #pragma unroll
      for (int mt = 0; mt < 2; mt++)
        #pragma unroll
        for (int nt = 0; nt < 4; nt++) acc[mt][nt] = (f32x4)(0.0f);
      #pragma unroll
      for (int k = 0; k < 4; k++) {
        f16x8 af0 = *(const f16x8*)&U[(r)*136      + k*32 + q*8];
        f16x8 af1 = *(const f16x8*)&U[(16 + r)*136 + k*32 + q*8];
        #pragma unroll
        for (int nt = 0; nt < 4; nt++) {
          acc[0][nt] = MFMA16(af0, bg4[nt][k], acc[0][nt]);
          acc[1][nt] = MFMA16(af1, bg4[nt][k], acc[1][nt]);
        }
      }
      #pragma unroll
      for (int mt = 0; mt < 2; mt++)
        #pragma unroll
        for (int nt = 0; nt < 4; nt++)
          #pragma unroll
          for (int j = 0; j < 4; j++)
            BU[(mt*16 + q*4 + j)*520 + n0 + nt*16 + r] = __float2half(acc[mt][nt][j]);
    }
    __syncthreads();
    // 32-step scan (final state only) -> SL
    if (tid < 256) {
      float sr = 0.0f, si = 0.0f;
      #pragma unroll
      for (int t = 0; t < 32; t++) {
        const float br = (float)BU[t*520 + h];
        const float bi = (float)BU[t*520 + 256 + h];
        const float nr = lr*sr - li*si + br;
        const float ni = lr*si + li*sr + bi;
        sr = nr; si = ni;
      }
      *((float2*)(ws + WOFF_SL) + ((size_t)b*NC32 + cb)*HH + h) = float2{sr, si};
    }
    __syncthreads();
  }
}

// ============================ k_carry: serial O(NC) chain ============================
__global__ void k_carry(float* __restrict__ ws, int i)
{
  const int b = blockIdx.x >> 2;                      // 64 blocks × 64 threads
  const int h = (blockIdx.x & 3)*64 + threadIdx.x;
  const float Lr = ws[WOFF_LAML + ((size_t)i*HH+h)*2+0];
  const float Li = ws[WOFF_LAML + ((size_t)i*HH+h)*2+1];
  float2* C = (float2*)(ws + WOFF_CARRY) + (size_t)b*NC32*HH + h;
  const float2* S = (const float2*)(ws + WOFF_SL) + (size_t)b*NC32*HH + h;
  float sr = 0.0f, si = 0.0f;
  C[0] = float2{0.0f, 0.0f};
  for (int c0 = 0; c0 < 120; c0 += 8) {
    float2 sl[8];
    #pragma unroll
    for (int j = 0; j < 8; j++) sl[j] = S[(size_t)(c0+j)*HH];
    #pragma unroll
    for (int j = 0; j < 8; j++) {
      const float nr = Lr*sr - Li*si + sl[j].x;
      const float ni = Lr*si + Li*sr + sl[j].y;
      sr = nr; si = ni;
      C[(size_t)(c0+j+1)*HH] = float2{sr, si};
    }
  }
  {
    float2 sl[7];
    #pragma unroll
    for (int j = 0; j < 7; j++) sl[j] = S[(size_t)(120+j)*HH];
    #pragma unroll
    for (int j = 0; j < 7; j++) {
      const float nr = Lr*sr - Li*si + sl[j].x;
      const float ni = Lr*si + Li*sr + sl[j].y;
      sr = nr; si = ni;
      C[(size_t)(121+j)*HH] = float2{sr, si};
    }
  }
}

// ============================ k_BC: BN + B-proj + scan + C-proj + MLP (all-LDS) ============================
__global__ __launch_bounds__(512, 4) void k_BC(
    const __half* __restrict__ hin, float* __restrict__ ws,
    const float* __restrict__ bnsg, const float* __restrict__ bnbg,
    const float* __restrict__ b1g, const float* __restrict__ b2g,
    const float* __restrict__ Dvg, int iblk, int islast)
{
  __shared__ __half U[32*136];     // BN'd input (also u for u*D)
  __shared__ __half BU[32*520];    // Bu -> h (in-place scan) -> G (cols 0..255)
  __shared__ __half YL[32*136];
  __shared__ float AC[256];
  __shared__ float DVs[128];
  const int tid = threadIdx.x, w = tid >> 6, l = tid & 63, q = l >> 4, r = l & 15;
  const int b = blockIdx.y, cbg = blockIdx.x;    // 32 groups × 4 chunks
  const __half* w16 = (const __half*)(ws + WOFF_W16);
  const int d = w*16 + r;
  const int h = tid & 255;

  if (tid < 128) {
    const float inv = 1.0f / (float)NROWS;
    const float s  = ws[WOFF_STATS + ((size_t)iblk*2+0)*DE + tid];
    const float sq = ws[WOFF_STATS + ((size_t)iblk*2+1)*DE + tid];
    const float mean = s*inv;
    const float var  = sq*inv - mean*mean;
    const float a = rsqrtf(var + EPSF) * bnsg[iblk*DE + tid];
    AC[tid]       = a;
    AC[128 + tid] = bnbg[iblk*DE + tid] - mean*a;
    DVs[tid] = Dvg[iblk*DE + tid];
  }

  // ---- tile-invariant scalars ----
  const float lr = ws[WOFF_LAM + ((size_t)iblk*HH+h)*2+0];
  const float li = ws[WOFF_LAM + ((size_t)iblk*HH+h)*2+1];
  float b1a[2], b1b[2];
  #pragma unroll
  for (int nt = 0; nt < 2; nt++) {
    const int ca = w*32 + nt*16 + r;
    b1a[nt] = b1g[(size_t)iblk*LDIM + ca];
    b1b[nt] = b1g[(size_t)iblk*LDIM + 256 + ca];
  }
  const float bb2 = b2g[(size_t)iblk*DE + d];
  const __half* BG  = w16 + HOFF_BG + (size_t)iblk*512*128;
  const __half* WC  = w16 + HOFF_WC + (size_t)iblk*128*512;
  const __half* W1T = w16 + HOFF_W1 + (size_t)iblk*512*128;
  const __half* W2T = w16 + HOFF_W2 + (size_t)iblk*128*256;
  const int n0 = w*64;
  const __half* yh = (const __half*)(ws + WOFF_Y);
  __half* hh = (__half*)(ws + WOFF_H);
  float s_acc = 0.0f, ss_acc = 0.0f;
  __syncthreads();

  for (int it = 0; it < 4; it++) {
    const int cb = cbg*4 + it;
    const int row0 = b*TT + cb*32;

    // carry prefetch (used after B-proj)
    float2 carry = float2{0.0f, 0.0f};
    if (tid < 256)
      carry = *((const float2*)(ws + WOFF_CARRY) + ((size_t)b*NC32 + cb)*HH + h);
    // residual prefetch
    float yv[8];
    #pragma unroll
    for (int mt = 0; mt < 2; mt++)
      #pragma unroll
      for (int j = 0; j < 4; j++)
        yv[mt*4+j] = (float)yh[(size_t)(row0 + mt*16 + q*4 + j)*DE + d];

    // P1: BN -> U
    {
      const int row = tid >> 4, d0 = (tid & 15)*8;
      f16x8 hv = *(const f16x8*)(hin + (size_t)(row0+row)*DE + d0);
      f16x8 uv;
      #pragma unroll
      for (int j = 0; j < 8; j++)
        uv[j] = (_Float16)((float)hv[j]*AC[d0+j] + AC[128+d0+j]);
      *(f16x8*)&U[row*136 + d0] = uv;
    }
    __syncthreads();

    // P2: B-proj (recompute) -> BU
    {
      f16x8 bg4[4][4];
      #pragma unroll
      for (int nt = 0; nt < 4; nt++)
        #pragma unroll
        for (int k = 0; k < 4; k++)
          bg4[nt][k] = *(const f16x8*)&BG[(size_t)(n0 + nt*16 + r)*128 + k*32 + q*8];
      f32x4 acc[2][4];
      #pragma unroll
      for (int mt = 0; mt < 2; mt++)
        #pragma unroll
        for (int nt = 0; nt < 4; nt++) acc[mt][nt] = (f32x4)(0.0f);
      #pragma unroll
      for (int k = 0; k < 4; k++) {
        f16x8 af0 = *(const f16x8*)&U[(r)*136      + k*32 + q*8];
        f16x8 af1 = *(const f16x8*)&U[(16 + r)*136 + k*32 + q*8];
        #pragma unroll
        for (int nt = 0; nt < 4; nt++) {
          acc[0][nt] = MFMA16(af0, bg4[nt][k], acc[0][nt]);
          acc[1][nt] = MFMA16(af1, bg4[nt][k], acc[1][nt]);
        }
      }
      #pragma unroll
      for (int mt = 0; mt < 2; mt++)
        #pragma unroll
        for (int nt = 0; nt < 4; nt++)
          #pragma unroll
          for (int j = 0; j < 4; j++)
            BU[(mt*16 + q*4 + j)*520 + n0 + nt*16 + r] = __float2half(acc[mt][nt][j]);
    }
    __syncthreads();

    // P3: in-place 32-step scan: BU[t] <- h_t
    if (tid < 256) {
      float sr = carry.x, si = carry.y;
      #pragma unroll
      for (int t = 0; t < 32; t++) {
        const float br = (float)BU[t*520 + h];
        const float bi = (float)BU[t*520 + 256 + h];
        const float nr = lr*sr - li*si + br;
        const float ni = lr*si + li*sr + bi;
        sr = nr; si = ni;
        BU[t*520 + h]       = __float2half(sr);
        BU[t*520 + 256 + h] = __float2half(si);
      }
    }
    __syncthreads();

    // P4: C-proj (K=512) + u*D -> YL
    {
      f16x8 wc[16];
      #pragma unroll
      for (int k = 0; k < 16; k++)
        wc[k] = *(const f16x8*)&WC[(size_t)d*512 + k*32 + q*8];
      f32x4 a0 = (f32x4)(0.0f), a1 = (f32x4)(0.0f);
      #pragma unroll
      for (int k = 0; k < 16; k++) {
        f16x8 af0 = *(const f16x8*)&BU[(r)*520      + k*32 + q*8];
        f16x8 af1 = *(const f16x8*)&BU[(16 + r)*520 + k*32 + q*8];
        a0 = MFMA16(af0, wc[k], a0);
        a1 = MFMA16(af1, wc[k], a1);
      }
      const float dv = DVs[d];
      #pragma unroll
      for (int mt = 0; mt < 2; mt++)
        #pragma unroll
        for (int j = 0; j < 4; j++) {
          const int t = mt*16 + q*4 + j;
          const float u = (float)U[t*136 + d];
          YL[t*136 + d] = __float2half((mt ? a1[j] : a0[j]) + u*dv);
        }
    }
    __syncthreads();

    // P5: W1 + GLU -> BU cols 0..255
    {
      f16x8 w1a[2][4], w1b[2][4];
      #pragma unroll
      for (int nt = 0; nt < 2; nt++) {
        const int ca = w*32 + nt*16 + r;
        #pragma unroll
        for (int k = 0; k < 4; k++) {
          w1a[nt][k] = *(const f16x8*)&W1T[(size_t)ca*128 + k*32 + q*8];
          w1b[nt][k] = *(const f16x8*)&W1T[(size_t)(256+ca)*128 + k*32 + q*8];
        }
      }
      #pragma unroll
      for (int nt = 0; nt < 2; nt++) {
        const int ca = w*32 + nt*16 + r;
        f32x4 aa0 = (f32x4)(0.0f), aa1 = (f32x4)(0.0f);
        f32x4 ab0 = (f32x4)(0.0f), ab1 = (f32x4)(0.0f);
        #pragma unroll
        for (int k = 0; k < 4; k++) {
          f16x8 af0 = *(const f16x8*)&YL[(r)*136      + k*32 + q*8];
          f16x8 af1 = *(const f16x8*)&YL[(16 + r)*136 + k*32 + q*8];
          aa0 = MFMA16(af0, w1a[nt][k], aa0);
          aa1 = MFMA16(af1, w1a[nt][k], aa1);
          ab0 = MFMA16(af0, w1b[nt][k], ab0);
          ab1 = MFMA16(af1, w1b[nt][k], ab1);
        }
        #pragma unroll
        for (int mt = 0; mt < 2; mt++)
          #pragma unroll
          for (int j = 0; j < 4; j++) {
            const int t = mt*16 + q*4 + j;
            const float av = (mt ? aa1[j] : aa0[j]) + b1a[nt];
            const float bv = (mt ? ab1[j] : ab0[j]) + b1b[nt];
            BU[t*520 + ca] = __float2half(av / (1.0f + __expf(-bv)));
          }
      }
    }
    __syncthreads();

    // P6: h' = G @ W2 + b2 + y
    {
      f16x8 w2f[8];
      #pragma unroll
      for (int k = 0; k < 8; k++)
        w2f[k] = *(const f16x8*)&W2T[(size_t)d*256 + k*32 + q*8];
      f32x4 a0 = (f32x4)(0.0f), a1 = (f32x4)(0.0f);
      #pragma unroll
      for (int k = 0; k < 8; k++) {
        f16x8 af0 = *(const f16x8*)&BU[(r)*520      + k*32 + q*8];
        f16x8 af1 = *(const f16x8*)&BU[(16 + r)*520 + k*32 + q*8];
        a0 = MFMA16(af0, w2f[k], a0);
        a1 = MFMA16(af1, w2f[k], a1);
      }
      #pragma unroll
      for (int mt = 0; mt < 2; mt++)
        #pragma unroll
        for (int j = 0; j < 4; j++) {
          const int t = mt*16 + q*4 + j;
          const size_t row = (size_t)(row0 + t);
          const float v = (mt ? a1[j] : a0[j]) + bb2 + yv[mt*4+j];
          hh[row*DE + d] = __float2half(v);
          s_acc += v; ss_acc += v*v;
        }
    }
    __syncthreads();
  }

  s_acc  += __shfl_xor(s_acc, 16);  s_acc  += __shfl_xor(s_acc, 32);
  ss_acc += __shfl_xor(ss_acc, 16); ss_acc += __shfl_xor(ss_acc, 32);
  if (l < 16) {
    atomicAdd(ws + WOFF_STATS + (size_t)((iblk+1)*2 + 0)*DE + d, s_acc);
    atomicAdd(ws + WOFF_STATS + (size_t)((iblk+1)*2 + 1)*DE + d, ss_acc);
    if (islast) atomicAdd(ws + WOFF_POOL + (size_t)b*DE + d, s_acc);
  }
}

// ============================ final projection ============================
__global__ void k_out(const float* __restrict__ Wout, const float* __restrict__ bout,
                      const float* __restrict__ ws, float* __restrict__ out)
{
  const int tid = threadIdx.x;
  if (tid < BB*ODIM) {
    const int b = tid / ODIM, o = tid % ODIM;
    float acc = bout[o];
    const float* p = ws + WOFF_POOL + (size_t)b*DE;
    const float invT = 1.0f / (float)TT;
    for (int d = 0; d < DE; d++) acc += p[d]*invT*Wout[d*ODIM + o];
    out[tid] = acc;
  }
}

extern "C" void kernel_launch(void* const* d_in, const int* in_sizes, int n_in,
                              void* d_out, int out_size, void* d_ws, size_t ws_size,
                              hipStream_t stream)
{
  const float* x   = (const float*)d_in[0];
  const float* nu  = (const float*)d_in[1];
  const float* th  = (const float*)d_in[2];
  const float* Bre = (const float*)d_in[3];
  const float* Bim = (const float*)d_in[4];
  const float* Cre = (const float*)d_in[5];
  const float* Cim = (const float*)d_in[6];
  const float* Dv  = (const float*)d_in[7];
  const float* W1  = (const float*)d_in[8];
  const float* b1  = (const float*)d_in[9];
  const float* W2  = (const float*)d_in[10];
  const float* b2  = (const float*)d_in[11];
  const float* bns = (const float*)d_in[12];
  const float* bnb = (const float*)d_in[13];
  const float* We  = (const float*)d_in[14];
  const float* be  = (const float*)d_in[15];
  const float* Wo  = (const float*)d_in[16];
  const float* bo  = (const float*)d_in[17];
  float* ws = (float*)d_ws;
  float* out = (float*)d_out;

  hipMemsetAsync(ws + WOFF_STATS, 0,
                 (size_t)(((NBLKS+1)*2*DE) + BB*DE)*sizeof(float), stream);

  k_prep<<<NBLKS, 256, 0, stream>>>(nu, th, Bre, Bim, Cre, Cim, W1, W2, We, ws);
  k_enc<<<NROWS/64, 512, 0, stream>>>(x, be, ws);

  const __half* Yh = (const __half*)(ws + WOFF_Y);
  const __half* Hh = (const __half*)(ws + WOFF_H);
  for (int i = 0; i < NBLKS; i++) {
    const __half* hin = (i == 0) ? Yh : Hh;
    k_A    <<<dim3(32, BB), 512, 0, stream>>>(hin, ws, bns, bnb, i);
    k_carry<<<64, 64, 0, stream>>>(ws, i);
    k_BC   <<<dim3(32, BB), 512, 0, stream>>>(hin, ws, bns, bnb, b1, b2, Dv, i,
                                              (i == NBLKS-1) ? 1 : 0);
  }
  k_out<<<1, 256, 0, stream>>>(Wo, bo, ws, out);
}

// Round 10
// 1079.840 us; speedup vs baseline: 1.0159x; 1.0159x over previous
//
#include <hip/hip_runtime.h>
#include <hip/hip_fp16.h>

#define BB 16
#define TT 4096
#define TSZ 64
#define DE 128
#define HH 256
#define LDIM 512
#define ODIM 10
#define NBLKS 6
#define EPSF 1e-5f
#define NC32 128          // 32-token chunks
#define NROWS (BB*TT)     // 65536

typedef _Float16 f16x8 __attribute__((ext_vector_type(8)));
typedef float f32x4 __attribute__((ext_vector_type(4)));
#define MFMA16(a,b,c) __builtin_amdgcn_mfma_f32_16x16x32_f16((a),(b),(c),0,0,0)

// ---- f16 weight region layout (offsets in halfs, base = ws + WOFF_W16) ----
enum : size_t {
  HOFF_BG = 0,                                  // [NBLK][512][128]  gamma*B rows (re|im)
  HOFF_WC = HOFF_BG + (size_t)NBLKS*512*128,    // [NBLK][128][512]  C-proj [d][hc]
  HOFF_W1 = HOFF_WC + (size_t)NBLKS*128*512,    // [NBLK][512][128]  W1^T [l][d]
  HOFF_W2 = HOFF_W1 + (size_t)NBLKS*512*128,    // [NBLK][128][256]  W2^T [d][g]
  HOFF_WE = HOFF_W2 + (size_t)NBLKS*128*256,    // [128][64]         Wenc^T
  HTOT_HALFS = HOFF_WE + 128*64
};

// ---- workspace layout (float offsets) ----
enum : size_t {
  WOFF_Y     = 0,                                    // __half [NROWS*DE]
  WOFF_H     = WOFF_Y + (size_t)NROWS*DE/2,          // __half [NROWS*DE]
  WOFF_W16   = WOFF_H + (size_t)NROWS*DE/2,          // f16 weights
  WOFF_LAM   = WOFF_W16 + (HTOT_HALFS+1)/2,          // [NBLK][256][2]
  WOFF_LAML  = WOFF_LAM + (size_t)NBLKS*HH*2,        // [NBLK][256][2] lam^32
  WOFF_SL    = WOFF_LAML + (size_t)NBLKS*HH*2,       // [B][128][256][2]
  WOFF_CARRY = WOFF_SL + (size_t)BB*NC32*HH*2,       // [B][128][256][2]
  WOFF_STATS = WOFF_CARRY + (size_t)BB*NC32*HH*2,    // [NBLK+1][2][128]
  WOFF_POOL  = WOFF_STATS + (size_t)(NBLKS+1)*2*DE,  // [B][128]
  WS_FLOATS  = WOFF_POOL + (size_t)BB*DE
};

// ============================ prep ============================
__global__ __launch_bounds__(256) void k_prep(
    const float* __restrict__ nu_log, const float* __restrict__ theta_log,
    const float* __restrict__ B_re, const float* __restrict__ B_im,
    const float* __restrict__ C_re, const float* __restrict__ C_im,
    const float* __restrict__ W1g, const float* __restrict__ W2g,
    const float* __restrict__ Wenc, float* __restrict__ ws)
{
  const int i = blockIdx.x, h = threadIdx.x;
  __half* w16 = (__half*)(ws + WOFF_W16);
  const float nu  = expf(nu_log[i*HH+h]);
  const float th  = expf(theta_log[i*HH+h]);
  const float mod = expf(-nu);
  const float lr = mod*cosf(th), li = mod*sinf(th);
  const float gamma = sqrtf(fmaxf(1.0f - mod*mod, 1e-8f));
  ws[WOFF_LAM + ((size_t)i*HH+h)*2+0] = lr;
  ws[WOFF_LAM + ((size_t)i*HH+h)*2+1] = li;
  {
    float ar = lr, ai = li;
    #pragma unroll
    for (int q = 0; q < 5; q++) { float nr=ar*ar-ai*ai, ni=2.0f*ar*ai; ar=nr; ai=ni; }
    ws[WOFF_LAML + ((size_t)i*HH+h)*2+0] = ar;   // lam^32
    ws[WOFF_LAML + ((size_t)i*HH+h)*2+1] = ai;
  }
  // BG [512][128]
  {
    __half* bg = w16 + HOFF_BG + (size_t)i*512*128;
    const float* bre = B_re + ((size_t)i*HH+h)*DE;
    const float* bim = B_im + ((size_t)i*HH+h)*DE;
    for (int d = 0; d < DE; d++) {
      bg[(size_t)h*128 + d]       = __float2half(bre[d]*gamma);
      bg[(size_t)(256+h)*128 + d] = __float2half(bim[d]*gamma);
    }
  }
  // WC [128][512]
  {
    __half* wc = w16 + HOFF_WC + (size_t)i*128*512;
    const float* cre = C_re + (size_t)i*DE*HH;
    const float* cim = C_im + (size_t)i*DE*HH;
    for (int d = 0; d < DE; d++) {
      wc[(size_t)d*512 + h]       = __float2half( cre[(size_t)d*HH + h]);
      wc[(size_t)d*512 + 256 + h] = __float2half(-cim[(size_t)d*HH + h]);
    }
  }
  // W1T [512][128]
  {
    __half* w1t = w16 + HOFF_W1 + (size_t)i*512*128;
    for (int d = 0; d < DE; d++) {
      w1t[(size_t)h*128 + d]       = __float2half(W1g[((size_t)i*DE + d)*LDIM + h]);
      w1t[(size_t)(256+h)*128 + d] = __float2half(W1g[((size_t)i*DE + d)*LDIM + 256 + h]);
    }
  }
  // W2T [128][256]
  if (h < 128) {
    __half* w2t = w16 + HOFF_W2 + (size_t)i*128*256;
    for (int g = 0; g < 256; g++)
      w2t[(size_t)h*256 + g] = __float2half(W2g[((size_t)i*256 + g)*DE + h]);
  }
  // WencT [128][64]
  if (i == 0 && h < 128) {
    __half* wet = w16 + HOFF_WE;
    for (int k = 0; k < TSZ; k++)
      wet[(size_t)h*TSZ + k] = __float2half(Wenc[(size_t)k*DE + h]);
  }
}

// ============================ encoder (coalesced staged output) ============================
__global__ __launch_bounds__(512) void k_enc(
    const float* __restrict__ x, const float* __restrict__ benc, float* __restrict__ ws)
{
  __shared__ __half XT[64*72];
  __shared__ __half YS[64*136];
  const int tid = threadIdx.x, w = tid >> 6, l = tid & 63;
  const size_t row0 = (size_t)blockIdx.x * 64;
  {
    const float4* xg = (const float4*)(x + row0*TSZ);
    for (int idx = tid; idx < 1024; idx += 512) {
      float4 v = xg[idx];
      const int r = idx >> 4, c4 = (idx & 15)*4;
      *(__half2*)&XT[r*72 + c4]     = __half2{__float2half(v.x), __float2half(v.y)};
      *(__half2*)&XT[r*72 + c4 + 2] = __half2{__float2half(v.z), __float2half(v.w)};
    }
  }
  __syncthreads();
  const __half* wet = (const __half*)(ws + WOFF_W16) + HOFF_WE;
  const int n0 = w*16;
  f32x4 acc[4];
  #pragma unroll
  for (int mt = 0; mt < 4; mt++) acc[mt] = (f32x4)(0.0f);
  #pragma unroll
  for (int k0 = 0; k0 < 64; k0 += 32) {
    f16x8 bf = *(const f16x8*)&wet[(size_t)(n0 + (l&15))*64 + k0 + (l>>4)*8];
    #pragma unroll
    for (int mt = 0; mt < 4; mt++) {
      f16x8 af = *(const f16x8*)&XT[(mt*16 + (l&15))*72 + k0 + (l>>4)*8];
      acc[mt] = MFMA16(af, bf, acc[mt]);
    }
  }
  const int d = n0 + (l&15);
  const float be = benc[d];
  float s = 0.0f, ss = 0.0f;
  #pragma unroll
  for (int mt = 0; mt < 4; mt++)
    #pragma unroll
    for (int j = 0; j < 4; j++) {
      const int t = mt*16 + (l>>4)*4 + j;
      const float v = acc[mt][j] + be;
      YS[t*136 + d] = __float2half(v);
      s += v; ss += v*v;
    }
  s  += __shfl_xor(s, 16);  s  += __shfl_xor(s, 32);
  ss += __shfl_xor(ss, 16); ss += __shfl_xor(ss, 32);
  if (l < 16) {
    atomicAdd(ws + WOFF_STATS + d, s);
    atomicAdd(ws + WOFF_STATS + DE + d, ss);
  }
  __syncthreads();
  // coalesced writeback
  __half* y = (__half*)(ws + WOFF_Y);
  const int row = tid >> 3, d0 = (tid & 7)*16;
  *(f16x8*)&y[(row0+row)*DE + d0]     = *(const f16x8*)&YS[row*136 + d0];
  *(f16x8*)&y[(row0+row)*DE + d0 + 8] = *(const f16x8*)&YS[row*136 + d0 + 8];
}

// ============================ k_A: BN + B-proj + LDS scan -> SL only ============================
__global__ __launch_bounds__(512, 4) void k_A(
    const __half* __restrict__ hin, float* __restrict__ ws,
    const float* __restrict__ bnsg, const float* __restrict__ bnbg, int iblk)
{
  __shared__ __half U[32*136];     // 8.5 KB
  __shared__ __half BU[32*520];    // 32.5 KB
  __shared__ float AC[256];
  const int tid = threadIdx.x, w = tid >> 6, l = tid & 63, q = l >> 4, r = l & 15;
  const int b = blockIdx.y, cbg = blockIdx.x;   // 32 groups × 4 chunks
  const int h = tid & 255;
  if (tid < 128) {
    const float inv = 1.0f / (float)NROWS;
    const float s  = ws[WOFF_STATS + ((size_t)iblk*2+0)*DE + tid];
    const float sq = ws[WOFF_STATS + ((size_t)iblk*2+1)*DE + tid];
    const float mean = s*inv;
    const float var  = sq*inv - mean*mean;
    const float a = rsqrtf(var + EPSF) * bnsg[iblk*DE + tid];
    AC[tid]       = a;
    AC[128 + tid] = bnbg[iblk*DE + tid] - mean*a;
  }
  const __half* BG = (const __half*)(ws + WOFF_W16) + HOFF_BG + (size_t)iblk*512*128;
  const int n0 = w*64;
  const float lr = ws[WOFF_LAM + ((size_t)iblk*HH+h)*2+0];
  const float li = ws[WOFF_LAM + ((size_t)iblk*HH+h)*2+1];
  f16x8 bg4[4][4];
  #pragma unroll
  for (int nt = 0; nt < 4; nt++)
    #pragma unroll
    for (int k = 0; k < 4; k++)
      bg4[nt][k] = *(const f16x8*)&BG[(size_t)(n0 + nt*16 + r)*128 + k*32 + q*8];
  __syncthreads();

  for (int it = 0; it < 4; it++) {
    const int cb = cbg*4 + it;
    const int row0 = b*TT + cb*32;
    // BN -> U
    {
      const int row = tid >> 4, d0 = (tid & 15)*8;
      f16x8 hv = *(const f16x8*)(hin + (size_t)(row0+row)*DE + d0);
      f16x8 uv;
      #pragma unroll
      for (int j = 0; j < 8; j++)
        uv[j] = (_Float16)((float)hv[j]*AC[d0+j] + AC[128+d0+j]);
      *(f16x8*)&U[row*136 + d0] = uv;
    }
    __syncthreads();
    // B-proj -> BU
    {
      f32x4 acc[2][4];
      #pragma unroll
      for (int mt = 0; mt < 2; mt++)
        #pragma unroll
        for (int nt = 0; nt < 4; nt++) acc[mt][nt] = (f32x4)(0.0f);
      #pragma unroll
      for (int k = 0; k < 4; k++) {
        f16x8 af0 = *(const f16x8*)&U[(r)*136      + k*32 + q*8];
        f16x8 af1 = *(const f16x8*)&U[(16 + r)*136 + k*32 + q*8];
        #pragma unroll
        for (int nt = 0; nt < 4; nt++) {
          acc[0][nt] = MFMA16(af0, bg4[nt][k], acc[0][nt]);
          acc[1][nt] = MFMA16(af1, bg4[nt][k], acc[1][nt]);
        }
      }
      #pragma unroll
      for (int mt = 0; mt < 2; mt++)
        #pragma unroll
        for (int nt = 0; nt < 4; nt++)
          #pragma unroll
          for (int j = 0; j < 4; j++)
            BU[(mt*16 + q*4 + j)*520 + n0 + nt*16 + r] = __float2half(acc[mt][nt][j]);
    }
    __syncthreads();
    // 32-step scan (final state only) -> SL
    if (tid < 256) {
      float sr = 0.0f, si = 0.0f;
      #pragma unroll
      for (int t = 0; t < 32; t++) {
        const float br = (float)BU[t*520 + h];
        const float bi = (float)BU[t*520 + 256 + h];
        const float nr = lr*sr - li*si + br;
        const float ni = lr*si + li*sr + bi;
        sr = nr; si = ni;
      }
      *((float2*)(ws + WOFF_SL) + ((size_t)b*NC32 + cb)*HH + h) = float2{sr, si};
    }
    __syncthreads();
  }
}

// ============================ k_carry: serial O(NC) chain ============================
__global__ void k_carry(float* __restrict__ ws, int i)
{
  const int b = blockIdx.x >> 2;                      // 64 blocks × 64 threads
  const int h = (blockIdx.x & 3)*64 + threadIdx.x;
  const float Lr = ws[WOFF_LAML + ((size_t)i*HH+h)*2+0];
  const float Li = ws[WOFF_LAML + ((size_t)i*HH+h)*2+1];
  float2* C = (float2*)(ws + WOFF_CARRY) + (size_t)b*NC32*HH + h;
  const float2* S = (const float2*)(ws + WOFF_SL) + (size_t)b*NC32*HH + h;
  float sr = 0.0f, si = 0.0f;
  C[0] = float2{0.0f, 0.0f};
  for (int c0 = 0; c0 < 120; c0 += 8) {
    float2 sl[8];
    #pragma unroll
    for (int j = 0; j < 8; j++) sl[j] = S[(size_t)(c0+j)*HH];
    #pragma unroll
    for (int j = 0; j < 8; j++) {
      const float nr = Lr*sr - Li*si + sl[j].x;
      const float ni = Lr*si + Li*sr + sl[j].y;
      sr = nr; si = ni;
      C[(size_t)(c0+j+1)*HH] = float2{sr, si};
    }
  }
  {
    float2 sl[7];
    #pragma unroll
    for (int j = 0; j < 7; j++) sl[j] = S[(size_t)(120+j)*HH];
    #pragma unroll
    for (int j = 0; j < 7; j++) {
      const float nr = Lr*sr - Li*si + sl[j].x;
      const float ni = Lr*si + Li*sr + sl[j].y;
      sr = nr; si = ni;
      C[(size_t)(121+j)*HH] = float2{sr, si};
    }
  }
}

// ============================ k_BC: BN + B-proj + scan + C-proj + MLP (all-LDS, coalesced I/O) ============================
__global__ __launch_bounds__(512, 4) void k_BC(
    const __half* __restrict__ hin, float* __restrict__ ws,
    const float* __restrict__ bnsg, const float* __restrict__ bnbg,
    const float* __restrict__ b1g, const float* __restrict__ b2g,
    const float* __restrict__ Dvg, int iblk, int islast)
{
  __shared__ __half U[32*136];     // BN'd input (u for u*D)
  __shared__ __half BU[32*520];    // Bu -> h (in-place scan) -> G (cols 0..255)
  __shared__ __half YL[32*136];
  __shared__ __half YR[32*136];    // residual y staging -> output staging
  __shared__ float AC[256];
  __shared__ float DVs[128];
  const int tid = threadIdx.x, w = tid >> 6, l = tid & 63, q = l >> 4, r = l & 15;
  const int b = blockIdx.y, cbg = blockIdx.x;    // 32 groups × 4 chunks
  const __half* w16 = (const __half*)(ws + WOFF_W16);
  const int d = w*16 + r;
  const int h = tid & 255;

  if (tid < 128) {
    const float inv = 1.0f / (float)NROWS;
    const float s  = ws[WOFF_STATS + ((size_t)iblk*2+0)*DE + tid];
    const float sq = ws[WOFF_STATS + ((size_t)iblk*2+1)*DE + tid];
    const float mean = s*inv;
    const float var  = sq*inv - mean*mean;
    const float a = rsqrtf(var + EPSF) * bnsg[iblk*DE + tid];
    AC[tid]       = a;
    AC[128 + tid] = bnbg[iblk*DE + tid] - mean*a;
    DVs[tid] = Dvg[iblk*DE + tid];
  }

  // ---- tile-invariant scalars ----
  const float lr = ws[WOFF_LAM + ((size_t)iblk*HH+h)*2+0];
  const float li = ws[WOFF_LAM + ((size_t)iblk*HH+h)*2+1];
  float b1a[2], b1b[2];
  #pragma unroll
  for (int nt = 0; nt < 2; nt++) {
    const int ca = w*32 + nt*16 + r;
    b1a[nt] = b1g[(size_t)iblk*LDIM + ca];
    b1b[nt] = b1g[(size_t)iblk*LDIM + 256 + ca];
  }
  const float bb2 = b2g[(size_t)iblk*DE + d];
  const __half* BG  = w16 + HOFF_BG + (size_t)iblk*512*128;
  const __half* WC  = w16 + HOFF_WC + (size_t)iblk*128*512;
  const __half* W1T = w16 + HOFF_W1 + (size_t)iblk*512*128;
  const __half* W2T = w16 + HOFF_W2 + (size_t)iblk*128*256;
  const int n0 = w*64;
  const __half* yh = (const __half*)(ws + WOFF_Y);
  __half* hh = (__half*)(ws + WOFF_H);
  float s_acc = 0.0f, ss_acc = 0.0f;
  __syncthreads();

  for (int it = 0; it < 4; it++) {
    const int cb = cbg*4 + it;
    const int row0 = b*TT + cb*32;

    // carry prefetch (used after B-proj)
    float2 carry = float2{0.0f, 0.0f};
    if (tid < 256)
      carry = *((const float2*)(ws + WOFF_CARRY) + ((size_t)b*NC32 + cb)*HH + h);

    // P1: coalesced loads — BN(hin) -> U, raw y -> YR
    {
      const int row = tid >> 4, d0 = (tid & 15)*8;
      f16x8 hv = *(const f16x8*)(hin + (size_t)(row0+row)*DE + d0);
      f16x8 yv8 = *(const f16x8*)(yh + (size_t)(row0+row)*DE + d0);
      f16x8 uv;
      #pragma unroll
      for (int j = 0; j < 8; j++)
        uv[j] = (_Float16)((float)hv[j]*AC[d0+j] + AC[128+d0+j]);
      *(f16x8*)&U[row*136 + d0]  = uv;
      *(f16x8*)&YR[row*136 + d0] = yv8;
    }
    __syncthreads();

    // P2: B-proj (recompute) -> BU
    {
      f16x8 bg4[4][4];
      #pragma unroll
      for (int nt = 0; nt < 4; nt++)
        #pragma unroll
        for (int k = 0; k < 4; k++)
          bg4[nt][k] = *(const f16x8*)&BG[(size_t)(n0 + nt*16 + r)*128 + k*32 + q*8];
      f32x4 acc[2][4];
      #pragma unroll
      for (int mt = 0; mt < 2; mt++)
        #pragma unroll
        for (int nt = 0; nt < 4; nt++) acc[mt][nt] = (f32x4)(0.0f);
      #pragma unroll
      for (int k = 0; k < 4; k++) {
        f16x8 af0 = *(const f16x8*)&U[(r)*136      + k*32 + q*8];
        f16x8 af1 = *(const f16x8*)&U[(16 + r)*136 + k*32 + q*8];
        #pragma unroll
        for (int nt = 0; nt < 4; nt++) {
          acc[0][nt] = MFMA16(af0, bg4[nt][k], acc[0][nt]);
          acc[1][nt] = MFMA16(af1, bg4[nt][k], acc[1][nt]);
        }
      }
      #pragma unroll
      for (int mt = 0; mt < 2; mt++)
        #pragma unroll
        for (int nt = 0; nt < 4; nt++)
          #pragma unroll
          for (int j = 0; j < 4; j++)
            BU[(mt*16 + q*4 + j)*520 + n0 + nt*16 + r] = __float2half(acc[mt][nt][j]);
    }
    __syncthreads();

    // P3: in-place 32-step scan: BU[t] <- h_t
    if (tid < 256) {
      float sr = carry.x, si = carry.y;
      #pragma unroll
      for (int t = 0; t < 32; t++) {
        const float br = (float)BU[t*520 + h];
        const float bi = (float)BU[t*520 + 256 + h];
        const float nr = lr*sr - li*si + br;
        const float ni = lr*si + li*sr + bi;
        sr = nr; si = ni;
        BU[t*520 + h]       = __float2half(sr);
        BU[t*520 + 256 + h] = __float2half(si);
      }
    }
    __syncthreads();

    // P4: C-proj (K=512) + u*D -> YL
    {
      f16x8 wc[16];
      #pragma unroll
      for (int k = 0; k < 16; k++)
        wc[k] = *(const f16x8*)&WC[(size_t)d*512 + k*32 + q*8];
      f32x4 a0 = (f32x4)(0.0f), a1 = (f32x4)(0.0f);
      #pragma unroll
      for (int k = 0; k < 16; k++) {
        f16x8 af0 = *(const f16x8*)&BU[(r)*520      + k*32 + q*8];
        f16x8 af1 = *(const f16x8*)&BU[(16 + r)*520 + k*32 + q*8];
        a0 = MFMA16(af0, wc[k], a0);
        a1 = MFMA16(af1, wc[k], a1);
      }
      const float dv = DVs[d];
      #pragma unroll
      for (int mt = 0; mt < 2; mt++)
        #pragma unroll
        for (int j = 0; j < 4; j++) {
          const int t = mt*16 + q*4 + j;
          const float u = (float)U[t*136 + d];
          YL[t*136 + d] = __float2half((mt ? a1[j] : a0[j]) + u*dv);
        }
    }
    __syncthreads();

    // P5: W1 + GLU -> BU cols 0..255
    {
      f16x8 w1a[2][4], w1b[2][4];
      #pragma unroll
      for (int nt = 0; nt < 2; nt++) {
        const int ca = w*32 + nt*16 + r;
        #pragma unroll
        for (int k = 0; k < 4; k++) {
          w1a[nt][k] = *(const f16x8*)&W1T[(size_t)ca*128 + k*32 + q*8];
          w1b[nt][k] = *(const f16x8*)&W1T[(size_t)(256+ca)*128 + k*32 + q*8];
        }
      }
      #pragma unroll
      for (int nt = 0; nt < 2; nt++) {
        const int ca = w*32 + nt*16 + r;
        f32x4 aa0 = (f32x4)(0.0f), aa1 = (f32x4)(0.0f);
        f32x4 ab0 = (f32x4)(0.0f), ab1 = (f32x4)(0.0f);
        #pragma unroll
        for (int k = 0; k < 4; k++) {
          f16x8 af0 = *(const f16x8*)&YL[(r)*136      + k*32 + q*8];
          f16x8 af1 = *(const f16x8*)&YL[(16 + r)*136 + k*32 + q*8];
          aa0 = MFMA16(af0, w1a[nt][k], aa0);
          aa1 = MFMA16(af1, w1a[nt][k], aa1);
          ab0 = MFMA16(af0, w1b[nt][k], ab0);
          ab1 = MFMA16(af1, w1b[nt][k], ab1);
        }
        #pragma unroll
        for (int mt = 0; mt < 2; mt++)
          #pragma unroll
          for (int j = 0; j < 4; j++) {
            const int t = mt*16 + q*4 + j;
            const float av = (mt ? aa1[j] : aa0[j]) + b1a[nt];
            const float bv = (mt ? ab1[j] : ab0[j]) + b1b[nt];
            BU[t*520 + ca] = __float2half(av / (1.0f + __expf(-bv)));
          }
      }
    }
    __syncthreads();

    // P6: h' = G @ W2 + b2 + y  -> stage into YR (in-place), stats in regs
    {
      f16x8 w2f[8];
      #pragma unroll
      for (int k = 0; k < 8; k++)
        w2f[k] = *(const f16x8*)&W2T[(size_t)d*256 + k*32 + q*8];
      f32x4 a0 = (f32x4)(0.0f), a1 = (f32x4)(0.0f);
      #pragma unroll
      for (int k = 0; k < 8; k++) {
        f16x8 af0 = *(const f16x8*)&BU[(r)*520      + k*32 + q*8];
        f16x8 af1 = *(const f16x8*)&BU[(16 + r)*520 + k*32 + q*8];
        a0 = MFMA16(af0, w2f[k], a0);
        a1 = MFMA16(af1, w2f[k], a1);
      }
      #pragma unroll
      for (int mt = 0; mt < 2; mt++)
        #pragma unroll
        for (int j = 0; j < 4; j++) {
          const int t = mt*16 + q*4 + j;
          const float v = (mt ? a1[j] : a0[j]) + bb2 + (float)YR[t*136 + d];
          YR[t*136 + d] = __float2half(v);
          s_acc += v; ss_acc += v*v;
        }
    }
    __syncthreads();

    // P7: coalesced writeback of h'
    {
      const int row = tid >> 4, d0 = (tid & 15)*8;
      *(f16x8*)(hh + (size_t)(row0+row)*DE + d0) = *(const f16x8*)&YR[row*136 + d0];
    }
    __syncthreads();
  }

  s_acc  += __shfl_xor(s_acc, 16);  s_acc  += __shfl_xor(s_acc, 32);
  ss_acc += __shfl_xor(ss_acc, 16); ss_acc += __shfl_xor(ss_acc, 32);
  if (l < 16) {
    atomicAdd(ws + WOFF_STATS + (size_t)((iblk+1)*2 + 0)*DE + d, s_acc);
    atomicAdd(ws + WOFF_STATS + (size_t)((iblk+1)*2 + 1)*DE + d, ss_acc);
    if (islast) atomicAdd(ws + WOFF_POOL + (size_t)b*DE + d, s_acc);
  }
}

// ============================ final projection ============================
__global__ void k_out(const float* __restrict__ Wout, const float* __restrict__ bout,
                      const float* __restrict__ ws, float* __restrict__ out)
{
  const int tid = threadIdx.x;
  if (tid < BB*ODIM) {
    const int b = tid / ODIM, o = tid % ODIM;
    float acc = bout[o];
    const float* p = ws + WOFF_POOL + (size_t)b*DE;
    const float invT = 1.0f / (float)TT;
    for (int d = 0; d < DE; d++) acc += p[d]*invT*Wout[d*ODIM + o];
    out[tid] = acc;
  }
}

extern "C" void kernel_launch(void* const* d_in, const int* in_sizes, int n_in,
                              void* d_out, int out_size, void* d_ws, size_t ws_size,
                              hipStream_t stream)
{
  const float* x   = (const float*)d_in[0];
  const float* nu  = (const float*)d_in[1];
  const float* th  = (const float*)d_in[2];
  const float* Bre = (const float*)d_in[3];
  const float* Bim = (const float*)d_in[4];
  const float* Cre = (const float*)d_in[5];
  const float* Cim = (const float*)d_in[6];
  const float* Dv  = (const float*)d_in[7];
  const float* W1  = (const float*)d_in[8];
  const float* b1  = (const float*)d_in[9];
  const float* W2  = (const float*)d_in[10];
  const float* b2  = (const float*)d_in[11];
  const float* bns = (const float*)d_in[12];
  const float* bnb = (const float*)d_in[13];
  const float* We  = (const float*)d_in[14];
  const float* be  = (const float*)d_in[15];
  const float* Wo  = (const float*)d_in[16];
  const float* bo  = (const float*)d_in[17];
  float* ws = (float*)d_ws;
  float* out = (float*)d_out;

  hipMemsetAsync(ws + WOFF_STATS, 0,
                 (size_t)(((NBLKS+1)*2*DE) + BB*DE)*sizeof(float), stream);

  k_prep<<<NBLKS, 256, 0, stream>>>(nu, th, Bre, Bim, Cre, Cim, W1, W2, We, ws);
  k_enc<<<NROWS/64, 512, 0, stream>>>(x, be, ws);

  const __half* Yh = (const __half*)(ws + WOFF_Y);
  const __half* Hh = (const __half*)(ws + WOFF_H);
  for (int i = 0; i < NBLKS; i++) {
    const __half* hin = (i == 0) ? Yh : Hh;
    k_A    <<<dim3(32, BB), 512, 0, stream>>>(hin, ws, bns, bnb, i);
    k_carry<<<64, 64, 0, stream>>>(ws, i);
    k_BC   <<<dim3(32, BB), 512, 0, stream>>>(hin, ws, bns, bnb, b1, b2, Dv, i,
                                              (i == NBLKS-1) ? 1 : 0);
  }
  k_out<<<1, 256, 0, stream>>>(Wo, bo, ws, out);
}

// Round 11
// 901.017 us; speedup vs baseline: 1.2175x; 1.1985x over previous
//
#include <hip/hip_runtime.h>
#include <hip/hip_fp16.h>

#define BB 16
#define TT 4096
#define TSZ 64
#define DE 128
#define HH 256
#define LDIM 512
#define ODIM 10
#define NBLKS 6
#define EPSF 1e-5f
#define NC32 128          // 32-token chunks
#define NROWS (BB*TT)     // 65536

typedef _Float16 f16x8 __attribute__((ext_vector_type(8)));
typedef _Float16 f16x4 __attribute__((ext_vector_type(4)));
typedef float f32x4 __attribute__((ext_vector_type(4)));
#define MFMA16(a,b,c) __builtin_amdgcn_mfma_f32_16x16x32_f16((a),(b),(c),0,0,0)

// ---- f16 weight region layout (offsets in halfs, base = ws + WOFF_W16) ----
enum : size_t {
  HOFF_BG = 0,                                  // [NBLK][512][128]  gamma*B rows (re|im)
  HOFF_WC = HOFF_BG + (size_t)NBLKS*512*128,    // [NBLK][128][512]  C-proj [d][2h|2h+1] = re,-im INTERLEAVED
  HOFF_W1 = HOFF_WC + (size_t)NBLKS*128*512,    // [NBLK][512][128]  W1^T [l][d]
  HOFF_W2 = HOFF_W1 + (size_t)NBLKS*512*128,    // [NBLK][128][256]  W2^T [d][g]
  HOFF_WE = HOFF_W2 + (size_t)NBLKS*128*256,    // [128][64]         Wenc^T
  HTOT_HALFS = HOFF_WE + 128*64
};

// ---- workspace layout (float offsets) ----
enum : size_t {
  WOFF_Y     = 0,                                    // __half [NROWS*DE]
  WOFF_H     = WOFF_Y + (size_t)NROWS*DE/2,          // __half [NROWS*DE]
  WOFF_W16   = WOFF_H + (size_t)NROWS*DE/2,          // f16 weights
  WOFF_LAM   = WOFF_W16 + (HTOT_HALFS+1)/2,          // [NBLK][256][2]
  WOFF_LAML  = WOFF_LAM + (size_t)NBLKS*HH*2,        // [NBLK][256][2] lam^32
  WOFF_SL    = WOFF_LAML + (size_t)NBLKS*HH*2,       // [B][128][256][2]
  WOFF_CARRY = WOFF_SL + (size_t)BB*NC32*HH*2,       // [B][128][256][2]
  WOFF_STATS = WOFF_CARRY + (size_t)BB*NC32*HH*2,    // [NBLK+1][2][128]
  WOFF_POOL  = WOFF_STATS + (size_t)(NBLKS+1)*2*DE,  // [B][128]
  WOFF_BU    = WOFF_POOL + (size_t)BB*DE,            // __half [B][128][512][32]
  WS_FLOATS  = WOFF_BU + (size_t)BB*NC32*512*32/2
};

// ============================ prep ============================
__global__ __launch_bounds__(256) void k_prep(
    const float* __restrict__ nu_log, const float* __restrict__ theta_log,
    const float* __restrict__ B_re, const float* __restrict__ B_im,
    const float* __restrict__ C_re, const float* __restrict__ C_im,
    const float* __restrict__ W1g, const float* __restrict__ W2g,
    const float* __restrict__ Wenc, float* __restrict__ ws)
{
  const int i = blockIdx.x, h = threadIdx.x;
  __half* w16 = (__half*)(ws + WOFF_W16);
  const float nu  = expf(nu_log[i*HH+h]);
  const float th  = expf(theta_log[i*HH+h]);
  const float mod = expf(-nu);
  const float lr = mod*cosf(th), li = mod*sinf(th);
  const float gamma = sqrtf(fmaxf(1.0f - mod*mod, 1e-8f));
  ws[WOFF_LAM + ((size_t)i*HH+h)*2+0] = lr;
  ws[WOFF_LAM + ((size_t)i*HH+h)*2+1] = li;
  {
    float ar = lr, ai = li;
    #pragma unroll
    for (int q = 0; q < 5; q++) { float nr=ar*ar-ai*ai, ni=2.0f*ar*ai; ar=nr; ai=ni; }
    ws[WOFF_LAML + ((size_t)i*HH+h)*2+0] = ar;   // lam^32
    ws[WOFF_LAML + ((size_t)i*HH+h)*2+1] = ai;
  }
  // BG [512][128]
  {
    __half* bg = w16 + HOFF_BG + (size_t)i*512*128;
    const float* bre = B_re + ((size_t)i*HH+h)*DE;
    const float* bim = B_im + ((size_t)i*HH+h)*DE;
    for (int d = 0; d < DE; d++) {
      bg[(size_t)h*128 + d]       = __float2half(bre[d]*gamma);
      bg[(size_t)(256+h)*128 + d] = __float2half(bim[d]*gamma);
    }
  }
  // WC [128][512] INTERLEAVED: [d][2h] = C_re[d][h], [d][2h+1] = -C_im[d][h]
  {
    __half* wc = w16 + HOFF_WC + (size_t)i*128*512;
    const float* cre = C_re + (size_t)i*DE*HH;
    const float* cim = C_im + (size_t)i*DE*HH;
    for (int d = 0; d < DE; d++) {
      wc[(size_t)d*512 + 2*h]     = __float2half( cre[(size_t)d*HH + h]);
      wc[(size_t)d*512 + 2*h + 1] = __float2half(-cim[(size_t)d*HH + h]);
    }
  }
  // W1T [512][128]
  {
    __half* w1t = w16 + HOFF_W1 + (size_t)i*512*128;
    for (int d = 0; d < DE; d++) {
      w1t[(size_t)h*128 + d]       = __float2half(W1g[((size_t)i*DE + d)*LDIM + h]);
      w1t[(size_t)(256+h)*128 + d] = __float2half(W1g[((size_t)i*DE + d)*LDIM + 256 + h]);
    }
  }
  // W2T [128][256]
  if (h < 128) {
    __half* w2t = w16 + HOFF_W2 + (size_t)i*128*256;
    for (int g = 0; g < 256; g++)
      w2t[(size_t)h*256 + g] = __float2half(W2g[((size_t)i*256 + g)*DE + h]);
  }
  // WencT [128][64]
  if (i == 0 && h < 128) {
    __half* wet = w16 + HOFF_WE;
    for (int k = 0; k < TSZ; k++)
      wet[(size_t)h*TSZ + k] = __float2half(Wenc[(size_t)k*DE + h]);
  }
}

// ============================ encoder (coalesced staged output) ============================
__global__ __launch_bounds__(512) void k_enc(
    const float* __restrict__ x, const float* __restrict__ benc, float* __restrict__ ws)
{
  __shared__ __half XT[64*72];
  __shared__ __half YS[64*136];
  const int tid = threadIdx.x, w = tid >> 6, l = tid & 63;
  const size_t row0 = (size_t)blockIdx.x * 64;
  {
    const float4* xg = (const float4*)(x + row0*TSZ);
    for (int idx = tid; idx < 1024; idx += 512) {
      float4 v = xg[idx];
      const int r = idx >> 4, c4 = (idx & 15)*4;
      *(__half2*)&XT[r*72 + c4]     = __half2{__float2half(v.x), __float2half(v.y)};
      *(__half2*)&XT[r*72 + c4 + 2] = __half2{__float2half(v.z), __float2half(v.w)};
    }
  }
  __syncthreads();
  const __half* wet = (const __half*)(ws + WOFF_W16) + HOFF_WE;
  const int n0 = w*16;
  f32x4 acc[4];
  #pragma unroll
  for (int mt = 0; mt < 4; mt++) acc[mt] = (f32x4)(0.0f);
  #pragma unroll
  for (int k0 = 0; k0 < 64; k0 += 32) {
    f16x8 bf = *(const f16x8*)&wet[(size_t)(n0 + (l&15))*64 + k0 + (l>>4)*8];
    #pragma unroll
    for (int mt = 0; mt < 4; mt++) {
      f16x8 af = *(const f16x8*)&XT[(mt*16 + (l&15))*72 + k0 + (l>>4)*8];
      acc[mt] = MFMA16(af, bf, acc[mt]);
    }
  }
  const int d = n0 + (l&15);
  const float be = benc[d];
  float s = 0.0f, ss = 0.0f;
  #pragma unroll
  for (int mt = 0; mt < 4; mt++)
    #pragma unroll
    for (int j = 0; j < 4; j++) {
      const int t = mt*16 + (l>>4)*4 + j;
      const float v = acc[mt][j] + be;
      YS[t*136 + d] = __float2half(v);
      s += v; ss += v*v;
    }
  s  += __shfl_xor(s, 16);  s  += __shfl_xor(s, 32);
  ss += __shfl_xor(ss, 16); ss += __shfl_xor(ss, 32);
  if (l < 16) {
    atomicAdd(ws + WOFF_STATS + d, s);
    atomicAdd(ws + WOFF_STATS + DE + d, ss);
  }
  __syncthreads();
  __half* y = (__half*)(ws + WOFF_Y);
  const int row = tid >> 3, d0 = (tid & 7)*16;
  *(f16x8*)&y[(row0+row)*DE + d0]     = *(const f16x8*)&YS[row*136 + d0];
  *(f16x8*)&y[(row0+row)*DE + d0 + 8] = *(const f16x8*)&YS[row*136 + d0 + 8];
}

// ============================ k_A: BN + B-proj -> Bu(global) + LDS scan -> SL ============================
__global__ __launch_bounds__(512, 4) void k_A(
    const __half* __restrict__ hin, float* __restrict__ ws,
    const float* __restrict__ bnsg, const float* __restrict__ bnbg, int iblk)
{
  __shared__ __half U[32*136];     // 8.7 KB
  __shared__ __half BU[32*520];    // 33.3 KB
  __shared__ float AC[256];
  const int tid = threadIdx.x, w = tid >> 6, l = tid & 63, q = l >> 4, r = l & 15;
  const int b = blockIdx.y, cbg = blockIdx.x;   // 32 groups × 4 chunks
  const int h = tid & 255;
  if (tid < 128) {
    const float inv = 1.0f / (float)NROWS;
    const float s  = ws[WOFF_STATS + ((size_t)iblk*2+0)*DE + tid];
    const float sq = ws[WOFF_STATS + ((size_t)iblk*2+1)*DE + tid];
    const float mean = s*inv;
    const float var  = sq*inv - mean*mean;
    const float a = rsqrtf(var + EPSF) * bnsg[iblk*DE + tid];
    AC[tid]       = a;
    AC[128 + tid] = bnbg[iblk*DE + tid] - mean*a;
  }
  const __half* BG = (const __half*)(ws + WOFF_W16) + HOFF_BG + (size_t)iblk*512*128;
  const int n0 = w*64;
  const float lr = ws[WOFF_LAM + ((size_t)iblk*HH+h)*2+0];
  const float li = ws[WOFF_LAM + ((size_t)iblk*HH+h)*2+1];
  f16x8 bg4[4][4];
  #pragma unroll
  for (int nt = 0; nt < 4; nt++)
    #pragma unroll
    for (int k = 0; k < 4; k++)
      bg4[nt][k] = *(const f16x8*)&BG[(size_t)(n0 + nt*16 + r)*128 + k*32 + q*8];
  __half* bug = (__half*)(ws + WOFF_BU);
  __syncthreads();

  for (int it = 0; it < 4; it++) {
    const int cb = cbg*4 + it;
    const int row0 = b*TT + cb*32;
    // BN -> U
    {
      const int row = tid >> 4, d0 = (tid & 15)*8;
      f16x8 hv = *(const f16x8*)(hin + (size_t)(row0+row)*DE + d0);
      f16x8 uv;
      #pragma unroll
      for (int j = 0; j < 8; j++)
        uv[j] = (_Float16)((float)hv[j]*AC[d0+j] + AC[128+d0+j]);
      *(f16x8*)&U[row*136 + d0] = uv;
    }
    __syncthreads();
    // B-proj -> BU (LDS) + Bu (global, from regs)
    {
      f32x4 acc[2][4];
      #pragma unroll
      for (int mt = 0; mt < 2; mt++)
        #pragma unroll
        for (int nt = 0; nt < 4; nt++) acc[mt][nt] = (f32x4)(0.0f);
      #pragma unroll
      for (int k = 0; k < 4; k++) {
        f16x8 af0 = *(const f16x8*)&U[(r)*136      + k*32 + q*8];
        f16x8 af1 = *(const f16x8*)&U[(16 + r)*136 + k*32 + q*8];
        #pragma unroll
        for (int nt = 0; nt < 4; nt++) {
          acc[0][nt] = MFMA16(af0, bg4[nt][k], acc[0][nt]);
          acc[1][nt] = MFMA16(af1, bg4[nt][k], acc[1][nt]);
        }
      }
      #pragma unroll
      for (int mt = 0; mt < 2; mt++)
        #pragma unroll
        for (int nt = 0; nt < 4; nt++) {
          f16x4 pk;
          #pragma unroll
          for (int j = 0; j < 4; j++) {
            pk[j] = (_Float16)acc[mt][nt][j];
            BU[(mt*16 + q*4 + j)*520 + n0 + nt*16 + r] = __float2half(acc[mt][nt][j]);
          }
          const int hc = n0 + nt*16 + r;
          *(f16x4*)(bug + (((size_t)(b*NC32 + cb)*512 + hc)*32 + mt*16 + q*4)) = pk;
        }
    }
    __syncthreads();
    // 32-step scan (final state only) -> SL
    if (tid < 256) {
      float sr = 0.0f, si = 0.0f;
      #pragma unroll
      for (int t = 0; t < 32; t++) {
        const float br = (float)BU[t*520 + h];
        const float bi = (float)BU[t*520 + 256 + h];
        const float nr = lr*sr - li*si + br;
        const float ni = lr*si + li*sr + bi;
        sr = nr; si = ni;
      }
      *((float2*)(ws + WOFF_SL) + ((size_t)b*NC32 + cb)*HH + h) = float2{sr, si};
    }
    __syncthreads();
  }
}

// ============================ k_carry: serial O(NC) chain ============================
__global__ void k_carry(float* __restrict__ ws, int i)
{
  const int b = blockIdx.x >> 2;                      // 64 blocks × 64 threads
  const int h = (blockIdx.x & 3)*64 + threadIdx.x;
  const float Lr = ws[WOFF_LAML + ((size_t)i*HH+h)*2+0];
  const float Li = ws[WOFF_LAML + ((size_t)i*HH+h)*2+1];
  float2* C = (float2*)(ws + WOFF_CARRY) + (size_t)b*NC32*HH + h;
  const float2* S = (const float2*)(ws + WOFF_SL) + (size_t)b*NC32*HH + h;
  float sr = 0.0f, si = 0.0f;
  C[0] = float2{0.0f, 0.0f};
  for (int c0 = 0; c0 < 120; c0 += 8) {
    float2 sl[8];
    #pragma unroll
    for (int j = 0; j < 8; j++) sl[j] = S[(size_t)(c0+j)*HH];
    #pragma unroll
    for (int j = 0; j < 8; j++) {
      const float nr = Lr*sr - Li*si + sl[j].x;
      const float ni = Lr*si + Li*sr + sl[j].y;
      sr = nr; si = ni;
      C[(size_t)(c0+j+1)*HH] = float2{sr, si};
    }
  }
  {
    float2 sl[7];
    #pragma unroll
    for (int j = 0; j < 7; j++) sl[j] = S[(size_t)(120+j)*HH];
    #pragma unroll
    for (int j = 0; j < 7; j++) {
      const float nr = Lr*sr - Li*si + sl[j].x;
      const float ni = Lr*si + Li*sr + sl[j].y;
      sr = nr; si = ni;
      C[(size_t)(121+j)*HH] = float2{sr, si};
    }
  }
}

// ============================ k_BC: reg-scan + C-proj + MLP (5 barriers/tile) ============================
__global__ __launch_bounds__(512, 4) void k_BC(
    const __half* __restrict__ hin, float* __restrict__ ws,
    const float* __restrict__ bnsg, const float* __restrict__ bnbg,
    const float* __restrict__ b1g, const float* __restrict__ b2g,
    const float* __restrict__ Dvg, int iblk, int islast)
{
  __shared__ __half U[32*136];     // BN'd input (u for u*D)
  __shared__ __half HT[32*520];    // scan h INTERLEAVED (re,im) pairs -> later G (cols 0..255)
  __shared__ __half YL[32*136];
  __shared__ __half YR[32*136];    // residual staging -> output staging
  __shared__ float AC[256];
  __shared__ float DVs[128];
  const int tid = threadIdx.x, w = tid >> 6, l = tid & 63, q = l >> 4, r = l & 15;
  const int b = blockIdx.y, cbg = blockIdx.x;    // 32 groups × 4 chunks
  const __half* w16 = (const __half*)(ws + WOFF_W16);
  const int d = w*16 + r;
  const int h = tid & 255;

  if (tid < 128) {
    const float inv = 1.0f / (float)NROWS;
    const float s  = ws[WOFF_STATS + ((size_t)iblk*2+0)*DE + tid];
    const float sq = ws[WOFF_STATS + ((size_t)iblk*2+1)*DE + tid];
    const float mean = s*inv;
    const float var  = sq*inv - mean*mean;
    const float a = rsqrtf(var + EPSF) * bnsg[iblk*DE + tid];
    AC[tid]       = a;
    AC[128 + tid] = bnbg[iblk*DE + tid] - mean*a;
    DVs[tid] = Dvg[iblk*DE + tid];
  }

  // ---- tile-invariant scalars ----
  const float lr = ws[WOFF_LAM + ((size_t)iblk*HH+h)*2+0];
  const float li = ws[WOFF_LAM + ((size_t)iblk*HH+h)*2+1];
  float b1a[2], b1b[2];
  #pragma unroll
  for (int nt = 0; nt < 2; nt++) {
    const int ca = w*32 + nt*16 + r;
    b1a[nt] = b1g[(size_t)iblk*LDIM + ca];
    b1b[nt] = b1g[(size_t)iblk*LDIM + 256 + ca];
  }
  const float bb2 = b2g[(size_t)iblk*DE + d];
  const __half* WC  = w16 + HOFF_WC + (size_t)iblk*128*512;
  const __half* W1T = w16 + HOFF_W1 + (size_t)iblk*512*128;
  const __half* W2T = w16 + HOFF_W2 + (size_t)iblk*128*256;
  const __half* bug = (const __half*)(ws + WOFF_BU);
  const __half* yh = (const __half*)(ws + WOFF_Y);
  __half* hh = (__half*)(ws + WOFF_H);
  float s_acc = 0.0f, ss_acc = 0.0f;
  __syncthreads();

  for (int it = 0; it < 4; it++) {
    const int cb = cbg*4 + it;
    const int row0 = b*TT + cb*32;

    // P1: coalesced loads (hin->BN->U, y->YR), Bu->regs, carry; reg scan -> HT interleaved
    {
      const int row = tid >> 4, d0 = (tid & 15)*8;
      f16x8 hv  = *(const f16x8*)(hin + (size_t)(row0+row)*DE + d0);
      f16x8 yv8 = *(const f16x8*)(yh  + (size_t)(row0+row)*DE + d0);
      f16x8 uv;
      #pragma unroll
      for (int j = 0; j < 8; j++)
        uv[j] = (_Float16)((float)hv[j]*AC[d0+j] + AC[128+d0+j]);
      *(f16x8*)&U[row*136 + d0]  = uv;
      *(f16x8*)&YR[row*136 + d0] = yv8;
    }
    if (tid < 256) {
      const __half* bu = bug + ((size_t)(b*NC32 + cb)*512)*32;
      f16x8 bre[4], bim[4];
      #pragma unroll
      for (int k = 0; k < 4; k++) {
        bre[k] = *(const f16x8*)(bu + (size_t)h*32 + k*8);
        bim[k] = *(const f16x8*)(bu + (size_t)(256+h)*32 + k*8);
      }
      const float2 carry = *((const float2*)(ws + WOFF_CARRY) + ((size_t)b*NC32 + cb)*HH + h);
      float sr = carry.x, si = carry.y;
      #pragma unroll
      for (int t = 0; t < 32; t++) {
        const float br = (float)bre[t>>3][t&7];
        const float bi = (float)bim[t>>3][t&7];
        const float nr = lr*sr - li*si + br;
        const float ni = lr*si + li*sr + bi;
        sr = nr; si = ni;
        *(__half2*)&HT[t*520 + 2*h] = __half2{__float2half(sr), __float2half(si)};
      }
    }
    __syncthreads();

    // P2: C-proj (K=512 interleaved) + u*D -> YL
    {
      f16x8 wc[16];
      #pragma unroll
      for (int k = 0; k < 16; k++)
        wc[k] = *(const f16x8*)&WC[(size_t)d*512 + k*32 + q*8];
      f32x4 a0 = (f32x4)(0.0f), a1 = (f32x4)(0.0f);
      #pragma unroll
      for (int k = 0; k < 16; k++) {
        f16x8 af0 = *(const f16x8*)&HT[(r)*520      + k*32 + q*8];
        f16x8 af1 = *(const f16x8*)&HT[(16 + r)*520 + k*32 + q*8];
        a0 = MFMA16(af0, wc[k], a0);
        a1 = MFMA16(af1, wc[k], a1);
      }
      const float dv = DVs[d];
      #pragma unroll
      for (int mt = 0; mt < 2; mt++)
        #pragma unroll
        for (int j = 0; j < 4; j++) {
          const int t = mt*16 + q*4 + j;
          const float u = (float)U[t*136 + d];
          YL[t*136 + d] = __float2half((mt ? a1[j] : a0[j]) + u*dv);
        }
    }
    __syncthreads();

    // P3: W1 + GLU -> HT cols 0..255
    {
      #pragma unroll
      for (int nt = 0; nt < 2; nt++) {
        const int ca = w*32 + nt*16 + r;
        f16x8 wa[4], wb[4];
        #pragma unroll
        for (int k = 0; k < 4; k++) {
          wa[k] = *(const f16x8*)&W1T[(size_t)ca*128 + k*32 + q*8];
          wb[k] = *(const f16x8*)&W1T[(size_t)(256+ca)*128 + k*32 + q*8];
        }
        f32x4 aa0 = (f32x4)(0.0f), aa1 = (f32x4)(0.0f);
        f32x4 ab0 = (f32x4)(0.0f), ab1 = (f32x4)(0.0f);
        #pragma unroll
        for (int k = 0; k < 4; k++) {
          f16x8 af0 = *(const f16x8*)&YL[(r)*136      + k*32 + q*8];
          f16x8 af1 = *(const f16x8*)&YL[(16 + r)*136 + k*32 + q*8];
          aa0 = MFMA16(af0, wa[k], aa0);
          aa1 = MFMA16(af1, wa[k], aa1);
          ab0 = MFMA16(af0, wb[k], ab0);
          ab1 = MFMA16(af1, wb[k], ab1);
        }
        #pragma unroll
        for (int mt = 0; mt < 2; mt++)
          #pragma unroll
          for (int j = 0; j < 4; j++) {
            const int t = mt*16 + q*4 + j;
            const float av = (mt ? aa1[j] : aa0[j]) + b1a[nt];
            const float bv = (mt ? ab1[j] : ab0[j]) + b1b[nt];
            HT[t*520 + ca] = __float2half(av / (1.0f + __expf(-bv)));
          }
      }
    }
    __syncthreads();

    // P4: h' = G @ W2 + b2 + y -> YR (in place), stats
    {
      f16x8 w2f[8];
      #pragma unroll
      for (int k = 0; k < 8; k++)
        w2f[k] = *(const f16x8*)&W2T[(size_t)d*256 + k*32 + q*8];
      f32x4 a0 = (f32x4)(0.0f), a1 = (f32x4)(0.0f);
      #pragma unroll
      for (int k = 0; k < 8; k++) {
        f16x8 af0 = *(const f16x8*)&HT[(r)*520      + k*32 + q*8];
        f16x8 af1 = *(const f16x8*)&HT[(16 + r)*520 + k*32 + q*8];
        a0 = MFMA16(af0, w2f[k], a0);
        a1 = MFMA16(af1, w2f[k], a1);
      }
      #pragma unroll
      for (int mt = 0; mt < 2; mt++)
        #pragma unroll
        for (int j = 0; j < 4; j++) {
          const int t = mt*16 + q*4 + j;
          const float v = (mt ? a1[j] : a0[j]) + bb2 + (float)YR[t*136 + d];
          YR[t*136 + d] = __float2half(v);
          s_acc += v; ss_acc += v*v;
        }
    }
    __syncthreads();

    // P5: coalesced writeback
    {
      const int row = tid >> 4, d0 = (tid & 15)*8;
      *(f16x8*)(hh + (size_t)(row0+row)*DE + d0) = *(const f16x8*)&YR[row*136 + d0];
    }
    __syncthreads();
  }

  s_acc  += __shfl_xor(s_acc, 16);  s_acc  += __shfl_xor(s_acc, 32);
  ss_acc += __shfl_xor(ss_acc, 16); ss_acc += __shfl_xor(ss_acc, 32);
  if (l < 16) {
    atomicAdd(ws + WOFF_STATS + (size_t)((iblk+1)*2 + 0)*DE + d, s_acc);
    atomicAdd(ws + WOFF_STATS + (size_t)((iblk+1)*2 + 1)*DE + d, ss_acc);
    if (islast) atomicAdd(ws + WOFF_POOL + (size_t)b*DE + d, s_acc);
  }
}

// ============================ final projection ============================
__global__ void k_out(const float* __restrict__ Wout, const float* __restrict__ bout,
                      const float* __restrict__ ws, float* __restrict__ out)
{
  const int tid = threadIdx.x;
  if (tid < BB*ODIM) {
    const int b = tid / ODIM, o = tid % ODIM;
    float acc = bout[o];
    const float* p = ws + WOFF_POOL + (size_t)b*DE;
    const float invT = 1.0f / (float)TT;
    for (int d = 0; d < DE; d++) acc += p[d]*invT*Wout[d*ODIM + o];
    out[tid] = acc;
  }
}

extern "C" void kernel_launch(void* const* d_in, const int* in_sizes, int n_in,
                              void* d_out, int out_size, void* d_ws, size_t ws_size,
                              hipStream_t stream)
{
  const float* x   = (const float*)d_in[0];
  const float* nu  = (const float*)d_in[1];
  const float* th  = (const float*)d_in[2];
  const float* Bre = (const float*)d_in[3];
  const float* Bim = (const float*)d_in[4];
  const float* Cre = (const float*)d_in[5];
  const float* Cim = (const float*)d_in[6];
  const float* Dv  = (const float*)d_in[7];
  const float* W1  = (const float*)d_in[8];
  const float* b1  = (const float*)d_in[9];
  const float* W2  = (const float*)d_in[10];
  const float* b2  = (const float*)d_in[11];
  const float* bns = (const float*)d_in[12];
  const float* bnb = (const float*)d_in[13];
  const float* We  = (const float*)d_in[14];
  const float* be  = (const float*)d_in[15];
  const float* Wo  = (const float*)d_in[16];
  const float* bo  = (const float*)d_in[17];
  float* ws = (float*)d_ws;
  float* out = (float*)d_out;

  hipMemsetAsync(ws + WOFF_STATS, 0,
                 (size_t)(((NBLKS+1)*2*DE) + BB*DE)*sizeof(float), stream);

  k_prep<<<NBLKS, 256, 0, stream>>>(nu, th, Bre, Bim, Cre, Cim, W1, W2, We, ws);
  k_enc<<<NROWS/64, 512, 0, stream>>>(x, be, ws);

  const __half* Yh = (const __half*)(ws + WOFF_Y);
  const __half* Hh = (const __half*)(ws + WOFF_H);
  for (int i = 0; i < NBLKS; i++) {
    const __half* hin = (i == 0) ? Yh : Hh;
    k_A    <<<dim3(32, BB), 512, 0, stream>>>(hin, ws, bns, bnb, i);
    k_carry<<<64, 64, 0, stream>>>(ws, i);
    k_BC   <<<dim3(32, BB), 512, 0, stream>>>(hin, ws, bns, bnb, b1, b2, Dv, i,
                                              (i == NBLKS-1) ? 1 : 0);
  }
  k_out<<<1, 256, 0, stream>>>(Wo, bo, ws, out);
}

// Round 12
// 883.301 us; speedup vs baseline: 1.2419x; 1.0201x over previous
//
#include <hip/hip_runtime.h>
#include <hip/hip_fp16.h>

#define BB 16
#define TT 4096
#define TSZ 64
#define DE 128
#define HH 256
#define LDIM 512
#define ODIM 10
#define NBLKS 6
#define EPSF 1e-5f
#define NC32 128          // 32-token chunks
#define NROWS (BB*TT)     // 65536

typedef _Float16 f16x8 __attribute__((ext_vector_type(8)));
typedef _Float16 f16x4 __attribute__((ext_vector_type(4)));
typedef float f32x4 __attribute__((ext_vector_type(4)));
#define MFMA16(a,b,c) __builtin_amdgcn_mfma_f32_16x16x32_f16((a),(b),(c),0,0,0)

// ---- f16 weight region layout ----
enum : size_t {
  HOFF_BG = 0,                                  // [NBLK][512][128]
  HOFF_WC = HOFF_BG + (size_t)NBLKS*512*128,    // [NBLK][128][512]  [d][h]=Cre, [d][256+h]=-Cim
  HOFF_W1 = HOFF_WC + (size_t)NBLKS*128*512,    // [NBLK][512][128]
  HOFF_W2 = HOFF_W1 + (size_t)NBLKS*512*128,    // [NBLK][128][256]
  HOFF_WE = HOFF_W2 + (size_t)NBLKS*128*256,    // [128][64]
  HTOT_HALFS = HOFF_WE + 128*64
};

// ---- workspace layout (float offsets) ----
enum : size_t {
  WOFF_Y     = 0,
  WOFF_H     = WOFF_Y + (size_t)NROWS*DE/2,
  WOFF_W16   = WOFF_H + (size_t)NROWS*DE/2,
  WOFF_LAM   = WOFF_W16 + (HTOT_HALFS+1)/2,
  WOFF_LAML  = WOFF_LAM + (size_t)NBLKS*HH*2,
  WOFF_SL    = WOFF_LAML + (size_t)NBLKS*HH*2,
  WOFF_CARRY = WOFF_SL + (size_t)BB*NC32*HH*2,
  WOFF_STATS = WOFF_CARRY + (size_t)BB*NC32*HH*2,
  WOFF_POOL  = WOFF_STATS + (size_t)(NBLKS+1)*2*DE,
  WOFF_BU    = WOFF_POOL + (size_t)BB*DE,            // __half [B][128][512][32]
  WS_FLOATS  = WOFF_BU + (size_t)BB*NC32*512*32/2
};

// LDS strides (halfs)
#define SU 152
#define SH 280

// ============================ prep ============================
__global__ __launch_bounds__(256) void k_prep(
    const float* __restrict__ nu_log, const float* __restrict__ theta_log,
    const float* __restrict__ B_re, const float* __restrict__ B_im,
    const float* __restrict__ C_re, const float* __restrict__ C_im,
    const float* __restrict__ W1g, const float* __restrict__ W2g,
    const float* __restrict__ Wenc, float* __restrict__ ws)
{
  const int i = blockIdx.x, h = threadIdx.x;
  __half* w16 = (__half*)(ws + WOFF_W16);
  const float nu  = expf(nu_log[i*HH+h]);
  const float th  = expf(theta_log[i*HH+h]);
  const float mod = expf(-nu);
  const float lr = mod*cosf(th), li = mod*sinf(th);
  const float gamma = sqrtf(fmaxf(1.0f - mod*mod, 1e-8f));
  ws[WOFF_LAM + ((size_t)i*HH+h)*2+0] = lr;
  ws[WOFF_LAM + ((size_t)i*HH+h)*2+1] = li;
  {
    float ar = lr, ai = li;
    #pragma unroll
    for (int q = 0; q < 5; q++) { float nr=ar*ar-ai*ai, ni=2.0f*ar*ai; ar=nr; ai=ni; }
    ws[WOFF_LAML + ((size_t)i*HH+h)*2+0] = ar;
    ws[WOFF_LAML + ((size_t)i*HH+h)*2+1] = ai;
  }
  {
    __half* bg = w16 + HOFF_BG + (size_t)i*512*128;
    const float* bre = B_re + ((size_t)i*HH+h)*DE;
    const float* bim = B_im + ((size_t)i*HH+h)*DE;
    for (int d = 0; d < DE; d++) {
      bg[(size_t)h*128 + d]       = __float2half(bre[d]*gamma);
      bg[(size_t)(256+h)*128 + d] = __float2half(bim[d]*gamma);
    }
  }
  {
    __half* wc = w16 + HOFF_WC + (size_t)i*128*512;
    const float* cre = C_re + (size_t)i*DE*HH;
    const float* cim = C_im + (size_t)i*DE*HH;
    for (int d = 0; d < DE; d++) {
      wc[(size_t)d*512 + h]       = __float2half( cre[(size_t)d*HH + h]);
      wc[(size_t)d*512 + 256 + h] = __float2half(-cim[(size_t)d*HH + h]);
    }
  }
  {
    __half* w1t = w16 + HOFF_W1 + (size_t)i*512*128;
    for (int d = 0; d < DE; d++) {
      w1t[(size_t)h*128 + d]       = __float2half(W1g[((size_t)i*DE + d)*LDIM + h]);
      w1t[(size_t)(256+h)*128 + d] = __float2half(W1g[((size_t)i*DE + d)*LDIM + 256 + h]);
    }
  }
  if (h < 128) {
    __half* w2t = w16 + HOFF_W2 + (size_t)i*128*256;
    for (int g = 0; g < 256; g++)
      w2t[(size_t)h*256 + g] = __float2half(W2g[((size_t)i*256 + g)*DE + h]);
  }
  if (i == 0 && h < 128) {
    __half* wet = w16 + HOFF_WE;
    for (int k = 0; k < TSZ; k++)
      wet[(size_t)h*TSZ + k] = __float2half(Wenc[(size_t)k*DE + h]);
  }
}

// ============================ encoder ============================
__global__ __launch_bounds__(512) void k_enc(
    const float* __restrict__ x, const float* __restrict__ benc, float* __restrict__ ws)
{
  __shared__ __half XT[64*72];
  __shared__ __half YS[64*136];
  const int tid = threadIdx.x, w = tid >> 6, l = tid & 63;
  const size_t row0 = (size_t)blockIdx.x * 64;
  {
    const float4* xg = (const float4*)(x + row0*TSZ);
    for (int idx = tid; idx < 1024; idx += 512) {
      float4 v = xg[idx];
      const int r = idx >> 4, c4 = (idx & 15)*4;
      *(__half2*)&XT[r*72 + c4]     = __half2{__float2half(v.x), __float2half(v.y)};
      *(__half2*)&XT[r*72 + c4 + 2] = __half2{__float2half(v.z), __float2half(v.w)};
    }
  }
  __syncthreads();
  const __half* wet = (const __half*)(ws + WOFF_W16) + HOFF_WE;
  const int n0 = w*16;
  f32x4 acc[4];
  #pragma unroll
  for (int mt = 0; mt < 4; mt++) acc[mt] = (f32x4)(0.0f);
  #pragma unroll
  for (int k0 = 0; k0 < 64; k0 += 32) {
    f16x8 bf = *(const f16x8*)&wet[(size_t)(n0 + (l&15))*64 + k0 + (l>>4)*8];
    #pragma unroll
    for (int mt = 0; mt < 4; mt++) {
      f16x8 af = *(const f16x8*)&XT[(mt*16 + (l&15))*72 + k0 + (l>>4)*8];
      acc[mt] = MFMA16(af, bf, acc[mt]);
    }
  }
  const int d = n0 + (l&15);
  const float be = benc[d];
  float s = 0.0f, ss = 0.0f;
  #pragma unroll
  for (int mt = 0; mt < 4; mt++)
    #pragma unroll
    for (int j = 0; j < 4; j++) {
      const int t = mt*16 + (l>>4)*4 + j;
      const float v = acc[mt][j] + be;
      YS[t*136 + d] = __float2half(v);
      s += v; ss += v*v;
    }
  s  += __shfl_xor(s, 16);  s  += __shfl_xor(s, 32);
  ss += __shfl_xor(ss, 16); ss += __shfl_xor(ss, 32);
  if (l < 16) {
    atomicAdd(ws + WOFF_STATS + d, s);
    atomicAdd(ws + WOFF_STATS + DE + d, ss);
  }
  __syncthreads();
  __half* y = (__half*)(ws + WOFF_Y);
  const int row = tid >> 3, d0 = (tid & 7)*16;
  *(f16x8*)&y[(row0+row)*DE + d0]     = *(const f16x8*)&YS[row*136 + d0];
  *(f16x8*)&y[(row0+row)*DE + d0 + 8] = *(const f16x8*)&YS[row*136 + d0 + 8];
}

// ============================ k_A: BN + B-proj -> Bu(global) + LDS scan -> SL ============================
__global__ __launch_bounds__(512, 4) void k_A(
    const __half* __restrict__ hin, float* __restrict__ ws,
    const float* __restrict__ bnsg, const float* __restrict__ bnbg, int iblk)
{
  __shared__ __half U[32*136];
  __shared__ __half BU[32*536];
  __shared__ float AC[256];
  const int tid = threadIdx.x, w = tid >> 6, l = tid & 63, q = l >> 4, r = l & 15;
  const int b = blockIdx.y, cbg = blockIdx.x;
  const int h = tid & 255;
  if (tid < 128) {
    const float inv = 1.0f / (float)NROWS;
    const float s  = ws[WOFF_STATS + ((size_t)iblk*2+0)*DE + tid];
    const float sq = ws[WOFF_STATS + ((size_t)iblk*2+1)*DE + tid];
    const float mean = s*inv;
    const float var  = sq*inv - mean*mean;
    const float a = rsqrtf(var + EPSF) * bnsg[iblk*DE + tid];
    AC[tid]       = a;
    AC[128 + tid] = bnbg[iblk*DE + tid] - mean*a;
  }
  const __half* BG = (const __half*)(ws + WOFF_W16) + HOFF_BG + (size_t)iblk*512*128;
  const int n0 = w*64;
  const float lr = ws[WOFF_LAM + ((size_t)iblk*HH+h)*2+0];
  const float li = ws[WOFF_LAM + ((size_t)iblk*HH+h)*2+1];
  f16x8 bg4[4][4];
  #pragma unroll
  for (int nt = 0; nt < 4; nt++)
    #pragma unroll
    for (int k = 0; k < 4; k++)
      bg4[nt][k] = *(const f16x8*)&BG[(size_t)(n0 + nt*16 + r)*128 + k*32 + q*8];
  __half* bug = (__half*)(ws + WOFF_BU);
  __syncthreads();

  for (int it = 0; it < 4; it++) {
    const int cb = cbg*4 + it;
    const int row0 = b*TT + cb*32;
    {
      const int row = tid >> 4, d0 = (tid & 15)*8;
      f16x8 hv = *(const f16x8*)(hin + (size_t)(row0+row)*DE + d0);
      f16x8 uv;
      #pragma unroll
      for (int j = 0; j < 8; j++)
        uv[j] = (_Float16)((float)hv[j]*AC[d0+j] + AC[128+d0+j]);
      *(f16x8*)&U[row*136 + d0] = uv;
    }
    __syncthreads();
    {
      f32x4 acc[2][4];
      #pragma unroll
      for (int mt = 0; mt < 2; mt++)
        #pragma unroll
        for (int nt = 0; nt < 4; nt++) acc[mt][nt] = (f32x4)(0.0f);
      #pragma unroll
      for (int k = 0; k < 4; k++) {
        f16x8 af0 = *(const f16x8*)&U[(r)*136      + k*32 + q*8];
        f16x8 af1 = *(const f16x8*)&U[(16 + r)*136 + k*32 + q*8];
        #pragma unroll
        for (int nt = 0; nt < 4; nt++) {
          acc[0][nt] = MFMA16(af0, bg4[nt][k], acc[0][nt]);
          acc[1][nt] = MFMA16(af1, bg4[nt][k], acc[1][nt]);
        }
      }
      #pragma unroll
      for (int mt = 0; mt < 2; mt++)
        #pragma unroll
        for (int nt = 0; nt < 4; nt++) {
          f16x4 pk;
          #pragma unroll
          for (int j = 0; j < 4; j++) {
            pk[j] = (_Float16)acc[mt][nt][j];
            BU[(mt*16 + q*4 + j)*536 + n0 + nt*16 + r] = __float2half(acc[mt][nt][j]);
          }
          const int hc = n0 + nt*16 + r;
          *(f16x4*)(bug + (((size_t)(b*NC32 + cb)*512 + hc)*32 + mt*16 + q*4)) = pk;
        }
    }
    __syncthreads();
    if (tid < 256) {
      float sr = 0.0f, si = 0.0f;
      #pragma unroll
      for (int t = 0; t < 32; t++) {
        const float br = (float)BU[t*536 + h];
        const float bi = (float)BU[t*536 + 256 + h];
        const float nr = lr*sr - li*si + br;
        const float ni = lr*si + li*sr + bi;
        sr = nr; si = ni;
      }
      *((float2*)(ws + WOFF_SL) + ((size_t)b*NC32 + cb)*HH + h) = float2{sr, si};
    }
    __syncthreads();
  }
}

// ============================ k_carry ============================
__global__ void k_carry(float* __restrict__ ws, int i)
{
  const int b = blockIdx.x >> 2;
  const int h = (blockIdx.x & 3)*64 + threadIdx.x;
  const float Lr = ws[WOFF_LAML + ((size_t)i*HH+h)*2+0];
  const float Li = ws[WOFF_LAML + ((size_t)i*HH+h)*2+1];
  float2* C = (float2*)(ws + WOFF_CARRY) + (size_t)b*NC32*HH + h;
  const float2* S = (const float2*)(ws + WOFF_SL) + (size_t)b*NC32*HH + h;
  float sr = 0.0f, si = 0.0f;
  C[0] = float2{0.0f, 0.0f};
  for (int c0 = 0; c0 < 120; c0 += 8) {
    float2 sl[8];
    #pragma unroll
    for (int j = 0; j < 8; j++) sl[j] = S[(size_t)(c0+j)*HH];
    #pragma unroll
    for (int j = 0; j < 8; j++) {
      const float nr = Lr*sr - Li*si + sl[j].x;
      const float ni = Lr*si + Li*sr + sl[j].y;
      sr = nr; si = ni;
      C[(size_t)(c0+j+1)*HH] = float2{sr, si};
    }
  }
  {
    float2 sl[7];
    #pragma unroll
    for (int j = 0; j < 7; j++) sl[j] = S[(size_t)(120+j)*HH];
    #pragma unroll
    for (int j = 0; j < 7; j++) {
      const float nr = Lr*sr - Li*si + sl[j].x;
      const float ni = Lr*si + Li*sr + sl[j].y;
      sr = nr; si = ni;
      C[(size_t)(121+j)*HH] = float2{sr, si};
    }
  }
}

// ============================ k_BC: M=64 tiles, re/im-split C-proj ============================
__global__ __launch_bounds__(512, 4) void k_BC(
    const __half* __restrict__ hin, float* __restrict__ ws,
    const float* __restrict__ bnsg, const float* __restrict__ bnbg,
    const float* __restrict__ b1g, const float* __restrict__ b2g,
    const float* __restrict__ Dvg, int iblk, int islast)
{
  __shared__ __half U[64*SU];      // BN'd u  -> (P3) residual y -> (P4) h' staging
  __shared__ __half HT[64*SH];     // scan re -> scan im -> G
  __shared__ __half YL[64*SU];
  __shared__ float AC[256];
  __shared__ float DVs[128];
  const int tid = threadIdx.x, w = tid >> 6, l = tid & 63, q = l >> 4, r = l & 15;
  const int b = blockIdx.y, cbg = blockIdx.x;    // 32 groups × 4 chunks (2 tiles of 64 rows)
  const __half* w16 = (const __half*)(ws + WOFF_W16);
  const int d = w*16 + r;
  const int h = tid & 255, cl = tid >> 8;        // scan job: chunk-local cl, channel h

  if (tid < 128) {
    const float inv = 1.0f / (float)NROWS;
    const float s  = ws[WOFF_STATS + ((size_t)iblk*2+0)*DE + tid];
    const float sq = ws[WOFF_STATS + ((size_t)iblk*2+1)*DE + tid];
    const float mean = s*inv;
    const float var  = sq*inv - mean*mean;
    const float a = rsqrtf(var + EPSF) * bnsg[iblk*DE + tid];
    AC[tid]       = a;
    AC[128 + tid] = bnbg[iblk*DE + tid] - mean*a;
    DVs[tid] = Dvg[iblk*DE + tid];
  }

  const float lr = ws[WOFF_LAM + ((size_t)iblk*HH+h)*2+0];
  const float li = ws[WOFF_LAM + ((size_t)iblk*HH+h)*2+1];
  float b1a[2], b1b[2];
  #pragma unroll
  for (int nt = 0; nt < 2; nt++) {
    const int ca = w*32 + nt*16 + r;
    b1a[nt] = b1g[(size_t)iblk*LDIM + ca];
    b1b[nt] = b1g[(size_t)iblk*LDIM + 256 + ca];
  }
  const float bb2 = b2g[(size_t)iblk*DE + d];
  const __half* WC  = w16 + HOFF_WC + (size_t)iblk*128*512;
  const __half* W1T = w16 + HOFF_W1 + (size_t)iblk*512*128;
  const __half* W2T = w16 + HOFF_W2 + (size_t)iblk*128*256;
  const __half* bug = (const __half*)(ws + WOFF_BU);
  const __half* yh = (const __half*)(ws + WOFF_Y);
  __half* hh = (__half*)(ws + WOFF_H);
  float s_acc = 0.0f, ss_acc = 0.0f;
  __syncthreads();

  for (int it = 0; it < 2; it++) {               // 2 tiles × 64 rows
    const int cb0 = cbg*4 + it*2;                // first chunk of tile
    const int row0 = b*TT + cb0*32;

    // ---- P1: coalesced hin/y loads; BN -> U; y kept in regs; scan (si in regs) -> HT ----
    f16x8 yv0, yv1;
    {
      const int row = tid >> 3, d0 = (tid & 7)*16;
      const __half* hp = hin + (size_t)(row0+row)*DE + d0;
      f16x8 h0 = *(const f16x8*)hp, h1 = *(const f16x8*)(hp+8);
      yv0 = *(const f16x8*)(yh + (size_t)(row0+row)*DE + d0);
      yv1 = *(const f16x8*)(yh + (size_t)(row0+row)*DE + d0 + 8);
      f16x8 u0, u1;
      #pragma unroll
      for (int j = 0; j < 8; j++) {
        u0[j] = (_Float16)((float)h0[j]*AC[d0+j]   + AC[128+d0+j]);
        u1[j] = (_Float16)((float)h1[j]*AC[d0+8+j] + AC[128+d0+8+j]);
      }
      *(f16x8*)&U[row*SU + d0]     = u0;
      *(f16x8*)&U[row*SU + d0 + 8] = u1;
    }
    f16x8 si8[4];
    {
      const int cb = cb0 + cl;
      const __half* bu = bug + ((size_t)(b*NC32 + cb)*512)*32;
      f16x8 bre[4], bim[4];
      #pragma unroll
      for (int k = 0; k < 4; k++) {
        bre[k] = *(const f16x8*)(bu + (size_t)h*32 + k*8);
        bim[k] = *(const f16x8*)(bu + (size_t)(256+h)*32 + k*8);
      }
      const float2 carry = *((const float2*)(ws + WOFF_CARRY) + ((size_t)b*NC32 + cb)*HH + h);
      float sr = carry.x, si = carry.y;
      #pragma unroll
      for (int t = 0; t < 32; t++) {
        const float br = (float)bre[t>>3][t&7];
        const float bi = (float)bim[t>>3][t&7];
        const float nr = lr*sr - li*si + br;
        const float ni = lr*si + li*sr + bi;
        sr = nr; si = ni;
        HT[(cl*32 + t)*SH + h] = __float2half(sr);
        si8[t>>3][t&7] = (_Float16)si;
      }
    }
    __syncthreads();

    // ---- P2a: C-proj re-half (K=256) ----
    f32x4 acc[4];
    #pragma unroll
    for (int mt = 0; mt < 4; mt++) acc[mt] = (f32x4)(0.0f);
    {
      f16x8 wcre[8];
      #pragma unroll
      for (int k = 0; k < 8; k++)
        wcre[k] = *(const f16x8*)&WC[(size_t)d*512 + k*32 + q*8];
      #pragma unroll
      for (int k = 0; k < 8; k++)
        #pragma unroll
        for (int mt = 0; mt < 4; mt++) {
          f16x8 af = *(const f16x8*)&HT[(mt*16 + r)*SH + k*32 + q*8];
          acc[mt] = MFMA16(af, wcre[k], acc[mt]);
        }
    }
    __syncthreads();
    // ---- swap si into HT ----
    #pragma unroll
    for (int t = 0; t < 32; t++)
      HT[(cl*32 + t)*SH + h] = si8[t>>3][t&7];
    __syncthreads();
    // ---- P2b: C-proj im-half (K=256) + u*D -> YL ----
    {
      f16x8 wcim[8];
      #pragma unroll
      for (int k = 0; k < 8; k++)
        wcim[k] = *(const f16x8*)&WC[(size_t)d*512 + 256 + k*32 + q*8];
      #pragma unroll
      for (int k = 0; k < 8; k++)
        #pragma unroll
        for (int mt = 0; mt < 4; mt++) {
          f16x8 af = *(const f16x8*)&HT[(mt*16 + r)*SH + k*32 + q*8];
          acc[mt] = MFMA16(af, wcim[k], acc[mt]);
        }
      const float dv = DVs[d];
      #pragma unroll
      for (int mt = 0; mt < 4; mt++)
        #pragma unroll
        for (int j = 0; j < 4; j++) {
          const int t = mt*16 + q*4 + j;
          const float u = (float)U[t*SU + d];
          YL[t*SU + d] = __float2half(acc[mt][j] + u*dv);
        }
    }
    __syncthreads();

    // ---- P3: stage y into U (u consumed); W1 + GLU -> HT ----
    {
      const int row = tid >> 3, d0 = (tid & 7)*16;
      *(f16x8*)&U[row*SU + d0]     = yv0;
      *(f16x8*)&U[row*SU + d0 + 8] = yv1;
    }
    {
      #pragma unroll
      for (int nt = 0; nt < 2; nt++) {
        const int ca = w*32 + nt*16 + r;
        f16x8 wa[4], wb[4];
        #pragma unroll
        for (int k = 0; k < 4; k++) {
          wa[k] = *(const f16x8*)&W1T[(size_t)ca*128 + k*32 + q*8];
          wb[k] = *(const f16x8*)&W1T[(size_t)(256+ca)*128 + k*32 + q*8];
        }
        f32x4 aa[4], ab[4];
        #pragma unroll
        for (int mt = 0; mt < 4; mt++) { aa[mt] = (f32x4)(0.0f); ab[mt] = (f32x4)(0.0f); }
        #pragma unroll
        for (int k = 0; k < 4; k++)
          #pragma unroll
          for (int mt = 0; mt < 4; mt++) {
            f16x8 af = *(const f16x8*)&YL[(mt*16 + r)*SU + k*32 + q*8];
            aa[mt] = MFMA16(af, wa[k], aa[mt]);
            ab[mt] = MFMA16(af, wb[k], ab[mt]);
          }
        #pragma unroll
        for (int mt = 0; mt < 4; mt++)
          #pragma unroll
          for (int j = 0; j < 4; j++) {
            const int t = mt*16 + q*4 + j;
            const float av = aa[mt][j] + b1a[nt];
            const float bv = ab[mt][j] + b1b[nt];
            HT[t*SH + ca] = __float2half(av / (1.0f + __expf(-bv)));
          }
      }
    }
    __syncthreads();

    // ---- P4: h' = G @ W2 + b2 + y(U) -> U, stats ----
    {
      f16x8 w2f[8];
      #pragma unroll
      for (int k = 0; k < 8; k++)
        w2f[k] = *(const f16x8*)&W2T[(size_t)d*256 + k*32 + q*8];
      f32x4 a2[4];
      #pragma unroll
      for (int mt = 0; mt < 4; mt++) a2[mt] = (f32x4)(0.0f);
      #pragma unroll
      for (int k = 0; k < 8; k++)
        #pragma unroll
        for (int mt = 0; mt < 4; mt++) {
          f16x8 af = *(const f16x8*)&HT[(mt*16 + r)*SH + k*32 + q*8];
          a2[mt] = MFMA16(af, w2f[k], a2[mt]);
        }
      #pragma unroll
      for (int mt = 0; mt < 4; mt++)
        #pragma unroll
        for (int j = 0; j < 4; j++) {
          const int t = mt*16 + q*4 + j;
          const float v = a2[mt][j] + bb2 + (float)U[t*SU + d];
          U[t*SU + d] = __float2half(v);
          s_acc += v; ss_acc += v*v;
        }
    }
    __syncthreads();

    // ---- P5: coalesced writeback ----
    {
      const int row = tid >> 3, d0 = (tid & 7)*16;
      *(f16x8*)(hh + (size_t)(row0+row)*DE + d0)     = *(const f16x8*)&U[row*SU + d0];
      *(f16x8*)(hh + (size_t)(row0+row)*DE + d0 + 8) = *(const f16x8*)&U[row*SU + d0 + 8];
    }
    __syncthreads();
  }

  s_acc  += __shfl_xor(s_acc, 16);  s_acc  += __shfl_xor(s_acc, 32);
  ss_acc += __shfl_xor(ss_acc, 16); ss_acc += __shfl_xor(ss_acc, 32);
  if (l < 16) {
    atomicAdd(ws + WOFF_STATS + (size_t)((iblk+1)*2 + 0)*DE + d, s_acc);
    atomicAdd(ws + WOFF_STATS + (size_t)((iblk+1)*2 + 1)*DE + d, ss_acc);
    if (islast) atomicAdd(ws + WOFF_POOL + (size_t)b*DE + d, s_acc);
  }
}

// ============================ final projection ============================
__global__ void k_out(const float* __restrict__ Wout, const float* __restrict__ bout,
                      const float* __restrict__ ws, float* __restrict__ out)
{
  const int tid = threadIdx.x;
  if (tid < BB*ODIM) {
    const int b = tid / ODIM, o = tid % ODIM;
    float acc = bout[o];
    const float* p = ws + WOFF_POOL + (size_t)b*DE;
    const float invT = 1.0f / (float)TT;
    for (int d = 0; d < DE; d++) acc += p[d]*invT*Wout[d*ODIM + o];
    out[tid] = acc;
  }
}

extern "C" void kernel_launch(void* const* d_in, const int* in_sizes, int n_in,
                              void* d_out, int out_size, void* d_ws, size_t ws_size,
                              hipStream_t stream)
{
  const float* x   = (const float*)d_in[0];
  const float* nu  = (const float*)d_in[1];
  const float* th  = (const float*)d_in[2];
  const float* Bre = (const float*)d_in[3];
  const float* Bim = (const float*)d_in[4];
  const float* Cre = (const float*)d_in[5];
  const float* Cim = (const float*)d_in[6];
  const float* Dv  = (const float*)d_in[7];
  const float* W1  = (const float*)d_in[8];
  const float* b1  = (const float*)d_in[9];
  const float* W2  = (const float*)d_in[10];
  const float* b2  = (const float*)d_in[11];
  const float* bns = (const float*)d_in[12];
  const float* bnb = (const float*)d_in[13];
  const float* We  = (const float*)d_in[14];
  const float* be  = (const float*)d_in[15];
  const float* Wo  = (const float*)d_in[16];
  const float* bo  = (const float*)d_in[17];
  float* ws = (float*)d_ws;
  float* out = (float*)d_out;

  hipMemsetAsync(ws + WOFF_STATS, 0,
                 (size_t)(((NBLKS+1)*2*DE) + BB*DE)*sizeof(float), stream);

  k_prep<<<NBLKS, 256, 0, stream>>>(nu, th, Bre, Bim, Cre, Cim, W1, W2, We, ws);
  k_enc<<<NROWS/64, 512, 0, stream>>>(x, be, ws);

  const __half* Yh = (const __half*)(ws + WOFF_Y);
  const __half* Hh = (const __half*)(ws + WOFF_H);
  for (int i = 0; i < NBLKS; i++) {
    const __half* hin = (i == 0) ? Yh : Hh;
    k_A    <<<dim3(32, BB), 512, 0, stream>>>(hin, ws, bns, bnb, i);
    k_carry<<<64, 64, 0, stream>>>(ws, i);
    k_BC   <<<dim3(32, BB), 512, 0, stream>>>(hin, ws, bns, bnb, b1, b2, Dv, i,
                                              (i == NBLKS-1) ? 1 : 0);
  }
  k_out<<<1, 256, 0, stream>>>(Wo, bo, ws, out);
}